// Round 2
// baseline (4399.466 us; speedup 1.0000x reference)
//
#include <hip/hip_runtime.h>

#define NV 16384
#define EH 16256
#define EVV 16256
#define ED 16129
#define NE 48641
#define NT 32258
#define ND 32259
#define OUTERF 32258

typedef unsigned int u32;
typedef unsigned short u16;

// ---------------- ws layout ----------------
static __host__ __device__ constexpr size_t al256(size_t x) { return (x + 255) & ~(size_t)255; }
static constexpr size_t OFF_ACC   = 0;
static constexpr size_t OFF_R32   = 256;
static constexpr size_t OFF_FRK   = OFF_R32   + al256(NV * 4);
static constexpr size_t OFF_FVAL  = OFF_FRK   + al256(ND * 4);
static constexpr size_t OFF_FRV   = OFF_FVAL  + al256(ND * 4);
static constexpr size_t OFF_DVAL  = OFF_FRV   + al256(ND * 4);
static constexpr size_t OFF_EPP   = OFF_DVAL  + al256(NE * 4);
static constexpr size_t OFF_EPD   = OFF_EPP   + al256(NE * 4);
static constexpr size_t OFF_LPA   = OFF_EPD   + al256(NE * 4);
static constexpr size_t OFF_LPB   = OFF_LPA   + al256(NE * 8);
static constexpr size_t OFF_LDA   = OFF_LPB   + al256(NE * 8);
static constexpr size_t OFF_LDB   = OFF_LDA   + al256(NE * 8);
static constexpr size_t OFF_TKEY  = OFF_LDB   + al256(NE * 8);
static constexpr size_t OFF_TAB   = OFF_TKEY  + al256(NT * 4);   // also reused as mrec by k_pair
static constexpr size_t OFF_TDV   = OFF_TAB   + al256(NT * 4);
static constexpr size_t OFF_SRK   = OFF_TDV   + al256(NT * 4);   // sorted rank-pairs
static constexpr size_t OFF_SDV   = OFF_SRK   + al256(NT * 4);
static constexpr size_t OFF_CANDP = OFF_SDV   + al256(NT * 4);
static constexpr size_t OFF_CANDD = OFF_CANDP + al256(NV * 4);

__device__ __forceinline__ u32 fmap(float x) {
  u32 u = __float_as_uint(x);
  return (u & 0x80000000u) ? ~u : (u | 0x80000000u);
}
__device__ __forceinline__ float funmap(u32 m) {
  u32 u = (m & 0x80000000u) ? (m & 0x7FFFFFFFu) : ~m;
  return __uint_as_float(u);
}

__device__ __forceinline__ int findh(volatile u16* par, int x) {
  while (true) {
    int p = par[x];
    if (p == x) return x;
    int gp = par[p];
    if (gp == p) return p;
    par[x] = (u16)gp;
    x = gp;
  }
}

// ---------------- K0: init ----------------
// acc layout: F[0]=primal MST wsum, F[1]=sum beta, U[2]=max beta (fmap),
//             F[3]=sum fval(faces), F[4]=sum dv(dual tree edges), U[5]=max bar (fmap)
__global__ void k_init(float* accF, u32* accU, u32* r32, u32* frk) {
  int i = blockIdx.x * 256 + threadIdx.x;
  if (i < 6) { accF[i] = 0.f; }            // zero-bits == 0.0f == 0u, ok for U slots too
  if (i < NV) r32[i] = 0u;
  if (i < ND) frk[i] = 0u;
}

// ---------------- K1: face values + reductions ----------------
__global__ void k_build(const float* __restrict__ beta, float* fval, float* accF, u32* accU) {
  __shared__ float ls[4], lm[4];
  int bid = blockIdx.x, tid = threadIdx.x;
  if (bid < 64) {
    int v = (bid << 8) + tid;
    float b = beta[v];
    float s = b, m = b;
    for (int off = 32; off >= 1; off >>= 1) {
      s += __shfl_down(s, off);
      m = fmaxf(m, __shfl_down(m, off));
    }
    int wid = tid >> 6;
    if ((tid & 63) == 0) { ls[wid] = s; lm[wid] = m; }
    __syncthreads();
    if (tid == 0) {
      s = ls[0] + ls[1] + ls[2] + ls[3];
      m = fmaxf(fmaxf(lm[0], lm[1]), fmaxf(lm[2], lm[3]));
      atomicAdd(&accF[1], s);
      atomicMax(&accU[2], fmap(m));
    }
  } else {
    int t = ((bid - 64) << 8) + tid;
    float c = 0.f;
    if (t < NT) {
      int i, j, v0; float fv;
      if (t < ED) { i = t / 127; j = t - i * 127; v0 = (i << 7) + j;
        fv = fminf(fminf(beta[v0], beta[v0 + 128]), beta[v0 + 129]); }  // L(i,j)
      else { int u = t - ED; i = u / 127; j = u - i * 127; v0 = (i << 7) + j;
        fv = fminf(fminf(beta[v0], beta[v0 + 1]), beta[v0 + 129]); }    // U(i,j)
      c = -fv;
      fval[t] = -fv;
      if (t == 0) fval[OUTERF] = __builtin_inff();
    }
    for (int off = 32; off >= 1; off >>= 1) c += __shfl_down(c, off);
    int wid = tid >> 6;
    if ((tid & 63) == 0) ls[wid] = c;
    __syncthreads();
    if (tid == 0) atomicAdd(&accF[3], ls[0] + ls[1] + ls[2] + ls[3]);
  }
}

// ---------------- K2v: vertex ranks (ascending beta, id tiebreak) ----------------
__global__ void k_rankv(const float* __restrict__ beta, u32* r32) {
  int v = blockIdx.x * 256 + threadIdx.x;
  int c = blockIdx.y;
  float bv = beta[v];
  int u0 = c << 10;
  int cnt = 0;
#pragma unroll 8
  for (int u = u0; u < u0 + 1024; ++u) {
    float bu = beta[u];
    cnt += (bu < bv || (bu == bv && u < v)) ? 1 : 0;
  }
  if (cnt) atomicAdd(&r32[v], (u32)cnt);
}

// ---------------- K2f: face ranks (descending fval, id tiebreak) ----------------
__global__ void k_rankf(const float* __restrict__ fval, u32* frk) {
  int g = blockIdx.x * 256 + threadIdx.x;
  if (g >= ND) return;
  float fg = fval[g];
  int u0 = blockIdx.y * 4033;
  int u1 = min(u0 + 4033, ND);
  int cnt = 0;
#pragma unroll 8
  for (int u = u0; u < u1; ++u) {
    float fu = fval[u];
    cnt += (fu > fg || (fu == fg && u < g)) ? 1 : 0;
  }
  if (cnt) atomicAdd(&frk[g], (u32)cnt);
}

// ---------------- K2b: scatter rank->value table ----------------
__global__ void k_scatf(const float* __restrict__ fval, const u32* __restrict__ frk, float* frv) {
  int g = blockIdx.x * 256 + threadIdx.x;
  if (g < ND) frv[frk[g]] = fval[g];
}

// ---------------- K3: build edges ----------------
__global__ void k_edges(const float* __restrict__ beta, const u32* __restrict__ r32,
                        float* dvals, u32* epP, u32* epD, uint2* listP, uint2* listD) {
  int e = blockIdx.x * 256 + threadIdx.x;
  if (e >= NE) return;
  int eu, ev, fa, fb;
  if (e < EH) {                        // horizontal (i,j)-(i,j+1)
    int i = e / 127, j = e - (e / 127) * 127;
    eu = (i << 7) + j; ev = eu + 1;
    fa = (i < 127) ? (ED + i * 127 + j) : OUTERF;
    fb = (i >= 1) ? ((i - 1) * 127 + j) : OUTERF;
  } else if (e < EH + EVV) {           // vertical (i,j)-(i+1,j)
    int k = e - EH;
    int i = k >> 7, j = k & 127;
    eu = (i << 7) + j; ev = eu + 128;
    fa = (j < 127) ? (i * 127 + j) : OUTERF;
    fb = (j >= 1) ? (ED + i * 127 + (j - 1)) : OUTERF;
  } else {                             // diagonal (i,j)-(i+1,j+1)
    int k = e - EH - EVV;
    int i = k / 127, j = k - (k / 127) * 127;
    eu = (i << 7) + j; ev = eu + 129;
    fa = i * 127 + j; fb = ED + i * 127 + j;
  }
  float bu = beta[eu], bv = beta[ev];
  float dv = -fminf(bu, bv);
  int cv = (bu <= bv) ? eu : ev;
  u32 rr = r32[cv];
  dvals[e] = dv;
  u32 pp = (u32)eu | ((u32)ev << 16);
  u32 dd = (u32)fa | ((u32)fb << 16);
  epP[e] = pp;
  epD[e] = dd;
  listP[e] = make_uint2(((16383u - rr) << 17) | (u32)e, pp);
  listD[e] = make_uint2((rr << 17) | (u32)e, dd);
}

// ---------------- K4: Boruvka (block 0 = primal MST weight, block 1 = dual maxST) ----------------
__global__ __launch_bounds__(1024) void k_boruvka(
    const float* __restrict__ dvals, const u32* __restrict__ epP, const u32* __restrict__ epD,
    uint2* lPA, uint2* lPB, uint2* lDA, uint2* lDB,
    u32* candP, u32* candD,
    u32* treeKey, u32* treeAB, float* treeDV, float* accF) {
  const bool dual = (blockIdx.x != 0);
  const int Nn = dual ? ND : NV;
  const u32* ep = dual ? epD : epP;
  u32* cand = dual ? candD : candP;
  uint2* listA = dual ? lDA : lPA;
  uint2* listB = dual ? lDB : lPB;
  __shared__ u16 par[ND];
  __shared__ int nCur, nNxt, treeCnt, changed;
  __shared__ float wred[16];
  int tid = threadIdx.x;
  for (int v = tid; v < Nn; v += 1024) { par[v] = (u16)v; cand[v] = 0xFFFFFFFFu; }
  if (tid == 0) { nCur = NE; treeCnt = 0; }
  float wloc = 0.f;
  __syncthreads();
  for (int round = 0; round < 40; ++round) {
    uint2* cur = (round & 1) ? listB : listA;
    uint2* nxt = (round & 1) ? listA : listB;
    if (tid == 0) nNxt = 0;
    __syncthreads();
    int n = nCur;
    for (int i = tid; i < n; i += 1024) {
      uint2 rec = cur[i];
      int a = (int)(rec.y & 0xFFFFu), b = (int)(rec.y >> 16);
      int ra = findh((volatile u16*)par, a);
      int rb = findh((volatile u16*)par, b);
      if (ra != rb) {
        int pos = atomicAdd(&nNxt, 1);
        nxt[pos] = make_uint2(rec.x, (u32)ra | ((u32)rb << 16));
        atomicMin(&cand[ra], rec.x);
        atomicMin(&cand[rb], rec.x);
      }
    }
    __syncthreads();
    u32 hooks[32];
#pragma unroll
    for (int it = 0; it < 32; ++it) {
      hooks[it] = 0xFFFFFFFFu;
      int v = tid + (it << 10);
      if (v < Nn) {
        u32 c = ((volatile u32*)cand)[v];
        if (c != 0xFFFFFFFFu && par[v] == (u16)v) {
          int eid = (int)(c & 0x1FFFFu);
          u32 ab = ep[eid];
          int ea = (int)(ab & 0xFFFFu), eb = (int)(ab >> 16);
          int ra = findh((volatile u16*)par, ea);
          int rb = findh((volatile u16*)par, eb);
          int w = (ra == v) ? rb : ra;
          u32 cw = ((volatile u32*)cand)[w];
          bool mutual = (cw != 0xFFFFFFFFu) && ((int)(cw & 0x1FFFFu) == eid);
          if (!mutual || v < w) {
            hooks[it] = (u32)w;
            if (dual) {
              int pos = atomicAdd(&treeCnt, 1);
              treeKey[pos] = c; treeAB[pos] = ab;
              treeDV[pos] = dvals[eid];
              wloc += dvals[eid];
            } else {
              atomicAdd(&treeCnt, 1);
              wloc += dvals[eid];
            }
          }
        }
      }
    }
    __syncthreads();
#pragma unroll
    for (int it = 0; it < 32; ++it) {
      int v = tid + (it << 10);
      if (v < Nn && hooks[it] != 0xFFFFFFFFu) par[v] = (u16)hooks[it];
    }
    __syncthreads();
    for (int jr = 0; jr < 24; ++jr) {
      if (tid == 0) changed = 0;
      __syncthreads();
      for (int v = tid; v < Nn; v += 1024) {
        int p = par[v]; int pp = par[p];
        if (p != pp) { par[v] = (u16)pp; changed = 1; }
      }
      __syncthreads();
      if (!changed) break;
    }
    __syncthreads();
    if (tid == 0) nCur = nNxt;
    __syncthreads();
    if (treeCnt >= Nn - 1 || nCur == 0) break;
    for (int v = tid; v < Nn; v += 1024) cand[v] = 0xFFFFFFFFu;
    __syncthreads();
  }
  for (int off = 32; off >= 1; off >>= 1) wloc += __shfl_down(wloc, off);
  if ((tid & 63) == 0) wred[tid >> 6] = wloc;
  __syncthreads();
  if (tid == 0) {
    float s = 0.f;
    for (int w = 0; w < 16; ++w) s += wred[w];
    atomicAdd(&accF[dual ? 4 : 0], s);
  }
}

// ---------------- K5: counting-sort dual tree edges by rank bucket, map to rank-space ----------------
__global__ __launch_bounds__(1024) void k_sorttree(
    const u32* __restrict__ treeKey, const u32* __restrict__ treeAB, const float* __restrict__ treeDV,
    const u32* __restrict__ frk, u32* sRK, float* sDV, u32* gtmp) {
  __shared__ u32 cnt[NV];  // 64 KB
  int tid = threadIdx.x;
  for (int b = tid; b < NV; b += 1024) cnt[b] = 0u;
  __syncthreads();
  for (int t = tid; t < NT; t += 1024) atomicAdd(&cnt[treeKey[t] >> 17], 1u);
  __syncthreads();
  u32 loc[16]; u32 s = 0;
#pragma unroll
  for (int k = 0; k < 16; ++k) { loc[k] = s; s += cnt[(tid << 4) + k]; }
  int lane = tid & 63, wid = tid >> 6;
  u32 incl = s;
  for (int off = 1; off < 64; off <<= 1) {
    u32 o = __shfl_up(incl, off);
    if (lane >= off) incl += o;
  }
  if (lane == 63) gtmp[wid] = incl;
  __syncthreads();
  u32 wbase = 0;
  for (int w = 0; w < 16; ++w) { u32 tt = gtmp[w]; wbase += (w < wid) ? tt : 0u; }
  u32 base = wbase + incl - s;
#pragma unroll
  for (int k = 0; k < 16; ++k) cnt[(tid << 4) + k] = base + loc[k];
  __syncthreads();
  for (int t = tid; t < NT; t += 1024) {
    u32 key = treeKey[t];
    u32 ab = treeAB[t];
    u32 pos = atomicAdd(&cnt[key >> 17], 1u);
    sRK[pos] = frk[ab & 0xFFFFu] | (frk[ab >> 16] << 16);   // rank-space endpoints
    sDV[pos] = treeDV[t];
  }
}

// ---------------- K6: union-find pairing in rank-space (1 wave, conflict fast path) ----------------
// rank-space: root id == face rank; smaller rank = older (larger fval).
// Invariant: every root is its component's oldest face. Each edge merges (tree),
// the younger root y = max(ra,rb) dies; record mrec[idx] = y. Bars computed later.
__global__ __launch_bounds__(64) void k_pair(
    const u32* __restrict__ sRK, u32* __restrict__ mrec) {
  __shared__ u16 par[ND + 1];
  __shared__ u32 cntTab[8192];
  int lane = threadIdx.x;
  {
    u32* p32 = (u32*)par;
    for (int v = lane; v < (ND + 1) / 2; v += 64)
      p32[v] = ((2u * v + 1) << 16) | (2u * v);
  }
  for (int v = lane; v < 8192; v += 64) cntTab[v] = 0u;
  __syncthreads();
  const int nch = (NT + 63) >> 6;
  u32 abuf = sRK[lane];                       // prefetch chunk 0
  for (int ch = 0; ch < nch; ++ch) {
    int idx = (ch << 6) + lane;
    bool act = idx < NT;
    u32 ab = abuf;
    int idn = idx + 64;
    if (idn < NT) abuf = sRK[idn];            // prefetch next chunk
    u32 pr = 0xFFFFFFFFu;
    int ha = 0, hb = 0;
    if (act) {
      int ra = findh((volatile u16*)par, (int)(ab & 0xFFFFu));
      int rb = findh((volatile u16*)par, (int)(ab >> 16));
      pr = (u32)ra | ((u32)rb << 16);
      ha = ra & 8191; hb = rb & 8191;
      atomicAdd(&cntTab[ha], 1u);
      atomicAdd(&cntTab[hb], 1u);
    }
    __syncthreads();
    bool conf = false;
    if (act) conf = (cntTab[ha] > 1u) || (cntTab[hb] > 1u);
    __syncthreads();
    if (act) { cntTab[ha] = 0u; cntTab[hb] = 0u; }
    u32 myY = 0xFFFFFFFFu;
    if (act && !conf) {                       // parallel commit: roots disjoint
      u32 ra = pr & 0xFFFFu, rb = pr >> 16;
      u32 y = max(ra, rb), o = min(ra, rb);
      par[y] = (u16)o;
      myY = y;
    }
    unsigned long long mask = __ballot(act && conf);
    while (mask) {                            // serial commit for colliding edges, rank order
      int i = __ffsll((unsigned long long)mask) - 1;
      mask &= mask - 1;
      u32 P = (u32)__builtin_amdgcn_readlane((int)pr, i);
      u32 ra = P & 0xFFFFu, rb = P >> 16;
      u32 y = max(ra, rb), o = min(ra, rb);
      if (lane == i) myY = y;
      if (lane == 0) par[y] = (u16)o;
      u32 lo = pr & 0xFFFFu, hi = pr >> 16;
      lo = (lo == y) ? o : lo;
      hi = (hi == y) ? o : hi;
      pr = lo | (hi << 16);
    }
    if (myY != 0xFFFFFFFFu) mrec[idx] = myY;
    __syncthreads();
  }
}

// ---------------- K7: max bar reduction ----------------
__global__ void k_final(const u32* __restrict__ mrec, const float* __restrict__ sDV,
                        const float* __restrict__ frv, u32* accU) {
  __shared__ float lm[4];
  int tid = threadIdx.x;
  int idx = blockIdx.x * 256 + tid;
  float bar = 0.f;
  if (idx < NT) bar = frv[mrec[idx]] - sDV[idx];
  for (int off = 32; off >= 1; off >>= 1) bar = fmaxf(bar, __shfl_down(bar, off));
  if ((tid & 63) == 0) lm[tid >> 6] = bar;
  __syncthreads();
  if (tid == 0) {
    float m = fmaxf(fmaxf(lm[0], lm[1]), fmaxf(lm[2], lm[3]));
    atomicMax(&accU[5], fmap(m));
  }
}

// ---------------- K8: assemble output ----------------
__global__ void k_out(const float* __restrict__ accF, const u32* __restrict__ accU, float* out) {
  float loss0 = accF[0] + accF[1] - funmap(accU[2]);   // W_MST(f) + sum(beta) - max(beta)
  float sum1 = accF[3] - accF[4];                      // sum fval(faces) - sum dv(tree edges)
  float max1 = funmap(accU[5]);
  out[0] = loss0 + sum1 - max1;
}

extern "C" void kernel_launch(void* const* d_in, const int* in_sizes, int n_in,
                              void* d_out, int out_size, void* d_ws, size_t ws_size,
                              hipStream_t stream) {
  const float* beta = (const float*)d_in[0];
  float* out = (float*)d_out;
  char* ws = (char*)d_ws;
  float* accF = (float*)(ws + OFF_ACC);
  u32*   accU = (u32*)(ws + OFF_ACC);
  u32*   gtmp = (u32*)(ws + OFF_ACC + 64);
  u32* r32 = (u32*)(ws + OFF_R32);
  u32* frk = (u32*)(ws + OFF_FRK);
  float* fval = (float*)(ws + OFF_FVAL);
  float* frv = (float*)(ws + OFF_FRV);
  float* dvals = (float*)(ws + OFF_DVAL);
  u32* epP = (u32*)(ws + OFF_EPP);
  u32* epD = (u32*)(ws + OFF_EPD);
  uint2* lPA = (uint2*)(ws + OFF_LPA);
  uint2* lPB = (uint2*)(ws + OFF_LPB);
  uint2* lDA = (uint2*)(ws + OFF_LDA);
  uint2* lDB = (uint2*)(ws + OFF_LDB);
  u32* treeKey = (u32*)(ws + OFF_TKEY);
  u32* treeAB = (u32*)(ws + OFF_TAB);     // reused as mrec by k_pair/k_final
  float* treeDV = (float*)(ws + OFF_TDV);
  u32* sRK = (u32*)(ws + OFF_SRK);
  float* sDV = (float*)(ws + OFF_SDV);
  u32* candP = (u32*)(ws + OFF_CANDP);
  u32* candD = (u32*)(ws + OFF_CANDD);
  u32* mrec = treeAB;

  hipLaunchKernelGGL(k_init, dim3(127), dim3(256), 0, stream, accF, accU, r32, frk);
  hipLaunchKernelGGL(k_build, dim3(191), dim3(256), 0, stream, beta, fval, accF, accU);
  hipLaunchKernelGGL(k_rankv, dim3(64, 16), dim3(256), 0, stream, beta, r32);
  hipLaunchKernelGGL(k_rankf, dim3(127, 8), dim3(256), 0, stream, fval, frk);
  hipLaunchKernelGGL(k_scatf, dim3(127), dim3(256), 0, stream, fval, frk, frv);
  hipLaunchKernelGGL(k_edges, dim3(191), dim3(256), 0, stream, beta, r32, dvals, epP, epD, lPA, lDA);
  hipLaunchKernelGGL(k_boruvka, dim3(2), dim3(1024), 0, stream, dvals, epP, epD,
                     lPA, lPB, lDA, lDB, candP, candD, treeKey, treeAB, treeDV, accF);
  hipLaunchKernelGGL(k_sorttree, dim3(1), dim3(1024), 0, stream, treeKey, treeAB, treeDV, frk, sRK, sDV, gtmp);
  hipLaunchKernelGGL(k_pair, dim3(1), dim3(64), 0, stream, sRK, mrec);
  hipLaunchKernelGGL(k_final, dim3(127), dim3(256), 0, stream, mrec, sDV, frv, accU);
  hipLaunchKernelGGL(k_out, dim3(1), dim3(1), 0, stream, accF, accU, out);
}

// Round 3
// 4070.957 us; speedup vs baseline: 1.0807x; 1.0807x over previous
//
#include <hip/hip_runtime.h>

#define NV 16384
#define EH 16256
#define EVV 16256
#define ED 16129
#define NE 48641
#define NT 32258
#define ND 32259
#define OUTERF 32258

typedef unsigned int u32;
typedef unsigned short u16;

// ---------------- ws layout ----------------
static __host__ __device__ constexpr size_t al256(size_t x) { return (x + 255) & ~(size_t)255; }
static constexpr size_t OFF_ACC   = 0;
static constexpr size_t OFF_R32   = 256;
static constexpr size_t OFF_FRK   = OFF_R32   + al256(NV * 4);
static constexpr size_t OFF_FVAL  = OFF_FRK   + al256(ND * 4);
static constexpr size_t OFF_FRV   = OFF_FVAL  + al256(ND * 4);
static constexpr size_t OFF_DVAL  = OFF_FRV   + al256(ND * 4);
static constexpr size_t OFF_EPP   = OFF_DVAL  + al256(NE * 4);
static constexpr size_t OFF_EPD   = OFF_EPP   + al256(NE * 4);
static constexpr size_t OFF_LPA   = OFF_EPD   + al256(NE * 4);
static constexpr size_t OFF_LPB   = OFF_LPA   + al256(NE * 8);
static constexpr size_t OFF_LDA   = OFF_LPB   + al256(NE * 8);
static constexpr size_t OFF_LDB   = OFF_LDA   + al256(NE * 8);
static constexpr size_t OFF_TKEY  = OFF_LDB   + al256(NE * 8);
static constexpr size_t OFF_TAB   = OFF_TKEY  + al256(NT * 4);   // reused as mrec by k_pair
static constexpr size_t OFF_TDV   = OFF_TAB   + al256(NT * 4);
static constexpr size_t OFF_SRK   = OFF_TDV   + al256(NT * 4);   // sorted rank-pairs
static constexpr size_t OFF_SDV   = OFF_SRK   + al256(NT * 4);
static constexpr size_t OFF_CANDP = OFF_SDV   + al256(NT * 4);
static constexpr size_t OFF_CANDD = OFF_CANDP + al256(NV * 4);

__device__ __forceinline__ u32 fmap(float x) {
  u32 u = __float_as_uint(x);
  return (u & 0x80000000u) ? ~u : (u | 0x80000000u);
}
__device__ __forceinline__ float funmap(u32 m) {
  u32 u = (m & 0x80000000u) ? (m & 0x7FFFFFFFu) : ~m;
  return __uint_as_float(u);
}

__device__ __forceinline__ int findh(volatile u16* par, int x) {
  while (true) {
    int p = par[x];
    if (p == x) return x;
    int gp = par[p];
    if (gp == p) return p;
    par[x] = (u16)gp;
    x = gp;
  }
}

// ---------------- K0: init ----------------
// acc: F[0]=primal MST wsum, F[1]=sum beta, U[2]=max beta(fmap),
//      F[3]=sum fval(faces), F[4]=sum dv(dual tree), U[5]=max bar(fmap)
__global__ void k_init(float* accF, u32* accU, u32* r32, u32* frk) {
  int i = blockIdx.x * 256 + threadIdx.x;
  if (i < 6) accF[i] = 0.f;
  if (i < NV) r32[i] = 0u;
  if (i < ND) frk[i] = 0u;
}

// ---------------- K1: face values + reductions ----------------
__global__ void k_build(const float* __restrict__ beta, float* fval, float* accF, u32* accU) {
  __shared__ float ls[4], lm[4];
  int bid = blockIdx.x, tid = threadIdx.x;
  if (bid < 64) {
    int v = (bid << 8) + tid;
    float b = beta[v];
    float s = b, m = b;
    for (int off = 32; off >= 1; off >>= 1) {
      s += __shfl_down(s, off);
      m = fmaxf(m, __shfl_down(m, off));
    }
    int wid = tid >> 6;
    if ((tid & 63) == 0) { ls[wid] = s; lm[wid] = m; }
    __syncthreads();
    if (tid == 0) {
      s = ls[0] + ls[1] + ls[2] + ls[3];
      m = fmaxf(fmaxf(lm[0], lm[1]), fmaxf(lm[2], lm[3]));
      atomicAdd(&accF[1], s);
      atomicMax(&accU[2], fmap(m));
    }
  } else {
    int t = ((bid - 64) << 8) + tid;
    float c = 0.f;
    if (t < NT) {
      int i, j, v0; float fv;
      if (t < ED) { i = t / 127; j = t - i * 127; v0 = (i << 7) + j;
        fv = fminf(fminf(beta[v0], beta[v0 + 128]), beta[v0 + 129]); }  // L(i,j)
      else { int u = t - ED; i = u / 127; j = u - i * 127; v0 = (i << 7) + j;
        fv = fminf(fminf(beta[v0], beta[v0 + 1]), beta[v0 + 129]); }    // U(i,j)
      c = -fv;
      fval[t] = -fv;
      if (t == 0) fval[OUTERF] = __builtin_inff();
    }
    for (int off = 32; off >= 1; off >>= 1) c += __shfl_down(c, off);
    int wid = tid >> 6;
    if ((tid & 63) == 0) ls[wid] = c;
    __syncthreads();
    if (tid == 0) atomicAdd(&accF[3], ls[0] + ls[1] + ls[2] + ls[3]);
  }
}

// ---------------- K2v: vertex ranks ----------------
__global__ void k_rankv(const float* __restrict__ beta, u32* r32) {
  int v = blockIdx.x * 256 + threadIdx.x;
  int c = blockIdx.y;
  float bv = beta[v];
  int u0 = c << 10;
  int cnt = 0;
#pragma unroll 8
  for (int u = u0; u < u0 + 1024; ++u) {
    float bu = beta[u];
    cnt += (bu < bv || (bu == bv && u < v)) ? 1 : 0;
  }
  if (cnt) atomicAdd(&r32[v], (u32)cnt);
}

// ---------------- K2f: face ranks (descending fval, id tiebreak) ----------------
__global__ void k_rankf(const float* __restrict__ fval, u32* frk) {
  int g = blockIdx.x * 256 + threadIdx.x;
  if (g >= ND) return;
  float fg = fval[g];
  int u0 = blockIdx.y * 4033;
  int u1 = min(u0 + 4033, ND);
  int cnt = 0;
#pragma unroll 8
  for (int u = u0; u < u1; ++u) {
    float fu = fval[u];
    cnt += (fu > fg || (fu == fg && u < g)) ? 1 : 0;
  }
  if (cnt) atomicAdd(&frk[g], (u32)cnt);
}

// ---------------- K2b: scatter rank->value ----------------
__global__ void k_scatf(const float* __restrict__ fval, const u32* __restrict__ frk, float* frv) {
  int g = blockIdx.x * 256 + threadIdx.x;
  if (g < ND) frv[frk[g]] = fval[g];
}

// ---------------- K3: build edges ----------------
__global__ void k_edges(const float* __restrict__ beta, const u32* __restrict__ r32,
                        float* dvals, u32* epP, u32* epD, uint2* listP, uint2* listD) {
  int e = blockIdx.x * 256 + threadIdx.x;
  if (e >= NE) return;
  int eu, ev, fa, fb;
  if (e < EH) {
    int i = e / 127, j = e - (e / 127) * 127;
    eu = (i << 7) + j; ev = eu + 1;
    fa = (i < 127) ? (ED + i * 127 + j) : OUTERF;
    fb = (i >= 1) ? ((i - 1) * 127 + j) : OUTERF;
  } else if (e < EH + EVV) {
    int k = e - EH;
    int i = k >> 7, j = k & 127;
    eu = (i << 7) + j; ev = eu + 128;
    fa = (j < 127) ? (i * 127 + j) : OUTERF;
    fb = (j >= 1) ? (ED + i * 127 + (j - 1)) : OUTERF;
  } else {
    int k = e - EH - EVV;
    int i = k / 127, j = k - (k / 127) * 127;
    eu = (i << 7) + j; ev = eu + 129;
    fa = i * 127 + j; fb = ED + i * 127 + j;
  }
  float bu = beta[eu], bv = beta[ev];
  float dv = -fminf(bu, bv);
  int cv = (bu <= bv) ? eu : ev;
  u32 rr = r32[cv];
  dvals[e] = dv;
  u32 pp = (u32)eu | ((u32)ev << 16);
  u32 dd = (u32)fa | ((u32)fb << 16);
  epP[e] = pp;
  epD[e] = dd;
  listP[e] = make_uint2(((16383u - rr) << 17) | (u32)e, pp);
  listD[e] = make_uint2((rr << 17) | (u32)e, dd);
}

// ---------------- K4: Boruvka ----------------
__global__ __launch_bounds__(1024) void k_boruvka(
    const float* __restrict__ dvals, const u32* __restrict__ epP, const u32* __restrict__ epD,
    uint2* lPA, uint2* lPB, uint2* lDA, uint2* lDB,
    u32* candP, u32* candD,
    u32* treeKey, u32* treeAB, float* treeDV, float* accF) {
  const bool dual = (blockIdx.x != 0);
  const int Nn = dual ? ND : NV;
  const u32* ep = dual ? epD : epP;
  u32* cand = dual ? candD : candP;
  uint2* listA = dual ? lDA : lPA;
  uint2* listB = dual ? lDB : lPB;
  __shared__ u16 par[ND];
  __shared__ int nCur, nNxt, treeCnt, changed;
  __shared__ float wred[16];
  int tid = threadIdx.x;
  for (int v = tid; v < Nn; v += 1024) { par[v] = (u16)v; cand[v] = 0xFFFFFFFFu; }
  if (tid == 0) { nCur = NE; treeCnt = 0; }
  float wloc = 0.f;
  __syncthreads();
  for (int round = 0; round < 40; ++round) {
    uint2* cur = (round & 1) ? listB : listA;
    uint2* nxt = (round & 1) ? listA : listB;
    if (tid == 0) nNxt = 0;
    __syncthreads();
    int n = nCur;
    for (int i = tid; i < n; i += 1024) {
      uint2 rec = cur[i];
      int a = (int)(rec.y & 0xFFFFu), b = (int)(rec.y >> 16);
      int ra = findh((volatile u16*)par, a);
      int rb = findh((volatile u16*)par, b);
      if (ra != rb) {
        int pos = atomicAdd(&nNxt, 1);
        nxt[pos] = make_uint2(rec.x, (u32)ra | ((u32)rb << 16));
        atomicMin(&cand[ra], rec.x);
        atomicMin(&cand[rb], rec.x);
      }
    }
    __syncthreads();
    u32 hooks[32];
#pragma unroll
    for (int it = 0; it < 32; ++it) {
      hooks[it] = 0xFFFFFFFFu;
      int v = tid + (it << 10);
      if (v < Nn) {
        u32 c = ((volatile u32*)cand)[v];
        if (c != 0xFFFFFFFFu && par[v] == (u16)v) {
          int eid = (int)(c & 0x1FFFFu);
          u32 ab = ep[eid];
          int ea = (int)(ab & 0xFFFFu), eb = (int)(ab >> 16);
          int ra = findh((volatile u16*)par, ea);
          int rb = findh((volatile u16*)par, eb);
          int w = (ra == v) ? rb : ra;
          u32 cw = ((volatile u32*)cand)[w];
          bool mutual = (cw != 0xFFFFFFFFu) && ((int)(cw & 0x1FFFFu) == eid);
          if (!mutual || v < w) {
            hooks[it] = (u32)w;
            if (dual) {
              int pos = atomicAdd(&treeCnt, 1);
              treeKey[pos] = c; treeAB[pos] = ab;
              treeDV[pos] = dvals[eid];
              wloc += dvals[eid];
            } else {
              atomicAdd(&treeCnt, 1);
              wloc += dvals[eid];
            }
          }
        }
      }
    }
    __syncthreads();
#pragma unroll
    for (int it = 0; it < 32; ++it) {
      int v = tid + (it << 10);
      if (v < Nn && hooks[it] != 0xFFFFFFFFu) par[v] = (u16)hooks[it];
    }
    __syncthreads();
    for (int jr = 0; jr < 24; ++jr) {
      if (tid == 0) changed = 0;
      __syncthreads();
      for (int v = tid; v < Nn; v += 1024) {
        int p = par[v]; int pp = par[p];
        if (p != pp) { par[v] = (u16)pp; changed = 1; }
      }
      __syncthreads();
      if (!changed) break;
    }
    __syncthreads();
    if (tid == 0) nCur = nNxt;
    __syncthreads();
    if (treeCnt >= Nn - 1 || nCur == 0) break;
    for (int v = tid; v < Nn; v += 1024) cand[v] = 0xFFFFFFFFu;
    __syncthreads();
  }
  for (int off = 32; off >= 1; off >>= 1) wloc += __shfl_down(wloc, off);
  if ((tid & 63) == 0) wred[tid >> 6] = wloc;
  __syncthreads();
  if (tid == 0) {
    float s = 0.f;
    for (int w = 0; w < 16; ++w) s += wred[w];
    atomicAdd(&accF[dual ? 4 : 0], s);
  }
}

// ---------------- K5: counting-sort dual tree edges by rank, map to rank-space ----------------
__global__ __launch_bounds__(1024) void k_sorttree(
    const u32* __restrict__ treeKey, const u32* __restrict__ treeAB, const float* __restrict__ treeDV,
    const u32* __restrict__ frk, u32* sRK, float* sDV, u32* gtmp) {
  __shared__ u32 cnt[NV];
  int tid = threadIdx.x;
  for (int b = tid; b < NV; b += 1024) cnt[b] = 0u;
  __syncthreads();
  for (int t = tid; t < NT; t += 1024) atomicAdd(&cnt[treeKey[t] >> 17], 1u);
  __syncthreads();
  u32 loc[16]; u32 s = 0;
#pragma unroll
  for (int k = 0; k < 16; ++k) { loc[k] = s; s += cnt[(tid << 4) + k]; }
  int lane = tid & 63, wid = tid >> 6;
  u32 incl = s;
  for (int off = 1; off < 64; off <<= 1) {
    u32 o = __shfl_up(incl, off);
    if (lane >= off) incl += o;
  }
  if (lane == 63) gtmp[wid] = incl;
  __syncthreads();
  u32 wbase = 0;
  for (int w = 0; w < 16; ++w) { u32 tt = gtmp[w]; wbase += (w < wid) ? tt : 0u; }
  u32 base = wbase + incl - s;
#pragma unroll
  for (int k = 0; k < 16; ++k) cnt[(tid << 4) + k] = base + loc[k];
  __syncthreads();
  for (int t = tid; t < NT; t += 1024) {
    u32 key = treeKey[t];
    u32 ab = treeAB[t];
    u32 pos = atomicAdd(&cnt[key >> 17], 1u);
    sRK[pos] = frk[ab & 0xFFFFu] | (frk[ab >> 16] << 16);
    sDV[pos] = treeDV[t];
  }
}

// ---------------- K6: exact Kruskal pairing, 16-wave batched speculative ----------------
// rank-space: root id == face rank; smaller rank = older. Tree edges sorted by rank.
// Phase F (all 16 waves): pre-find roots for 1024 edges (latency hidden).
// Phase S (wave 0): 16 sub-chunks x 64; refresh roots (1-2 hops), conflict-detect
//   via LDS count table (symmetric; hash false-positives -> serial path = correct),
//   parallel commit disjoint edges, readlane-serial commit for colliders in rank order.
//   Only lgkmcnt waits inside (no vmcnt drains; mrec stores fly free).
// Phase C (all waves): one pointer-jump compression round.
__global__ __launch_bounds__(1024) void k_pair(
    const u32* __restrict__ sRK, u32* __restrict__ mrec) {
  __shared__ u16 par[ND + 1];   // 64520 B
  __shared__ u32 rp[1024];      // 4 KB
  __shared__ u32 ctab[8192];    // 32 KB
  int tid = threadIdx.x;
  int lane = tid & 63;
  int wid = tid >> 6;
  {
    u32* p32 = (u32*)par;
    for (int v = tid; v < (ND + 1) / 2; v += 1024)
      p32[v] = ((2u * v + 1) << 16) | (2u * v);
  }
  for (int v = tid; v < 8192; v += 1024) ctab[v] = 0u;
  __syncthreads();
  for (int b = 0; b < 32; ++b) {
    int base = b << 10;
    int bcnt = min(1024, NT - base);
    // ---- phase F: parallel pre-find (benign path-halving races) ----
    int idx = base + tid;
    if (idx < NT) {
      u32 ab = sRK[idx];
      int ra = findh((volatile u16*)par, (int)(ab & 0xFFFFu));
      int rb = findh((volatile u16*)par, (int)(ab >> 16));
      rp[tid] = (u32)ra | ((u32)rb << 16);
    }
    __syncthreads();
    // ---- phase S: wave 0 exact serial-order commit ----
    if (wid == 0) {
      int nsub = (bcnt + 63) >> 6;
      for (int sub = 0; sub < nsub; ++sub) {
        int li = (sub << 6) + lane;
        int si = base + li;
        bool sact = li < bcnt;
        u32 pr = 0;
        int ha = 0, hb = 0;
        if (sact) {
          u32 p0 = rp[li];
          int ra = findh((volatile u16*)par, (int)(p0 & 0xFFFFu));  // refresh (shallow)
          int rb = findh((volatile u16*)par, (int)(p0 >> 16));
          pr = (u32)ra | ((u32)rb << 16);
          ha = ra & 8191; hb = rb & 8191;
          atomicAdd(&ctab[ha], 1u);
          atomicAdd(&ctab[hb], 1u);
        }
        asm volatile("s_waitcnt lgkmcnt(0)" ::: "memory");
        u32 ca = sact ? ctab[ha] : 0u;
        u32 cb = sact ? ctab[hb] : 0u;
        asm volatile("s_waitcnt lgkmcnt(0)" ::: "memory");
        if (sact) { ctab[ha] = 0u; ctab[hb] = 0u; }
        bool conf = sact && (ca > 1u || cb > 1u);
        u32 myY = 0xFFFFFFFFu;
        if (sact && !conf) {
          u32 ra = pr & 0xFFFFu, rb = pr >> 16;
          u32 y = max(ra, rb), o = min(ra, rb);
          par[y] = (u16)o;
          myY = y;
        }
        unsigned long long mask = __ballot(conf);
        while (mask) {
          int i = __ffsll(mask) - 1;
          mask &= mask - 1;
          u32 P = (u32)__builtin_amdgcn_readlane((int)pr, i);
          u32 ra = P & 0xFFFFu, rb = P >> 16;
          u32 y = max(ra, rb), o = min(ra, rb);
          if (lane == i) myY = y;
          if (lane == 0) par[y] = (u16)o;
          u32 lo = pr & 0xFFFFu, hi = pr >> 16;
          lo = (lo == y) ? o : lo;
          hi = (hi == y) ? o : hi;
          pr = lo | (hi << 16);
        }
        if (sact) mrec[si] = myY;   // global store; NOT drained per sub-chunk
        asm volatile("s_waitcnt lgkmcnt(0)" ::: "memory");
      }
    }
    __syncthreads();
    // ---- phase C: one compression round ----
    for (int v = tid; v < ND; v += 1024) {
      int p = par[v]; int pp = par[p];
      if (p != pp) par[v] = (u16)pp;
    }
    __syncthreads();
  }
}

// ---------------- K7: max bar reduction ----------------
__global__ void k_final(const u32* __restrict__ mrec, const float* __restrict__ sDV,
                        const float* __restrict__ frv, u32* accU) {
  __shared__ float lm[4];
  int tid = threadIdx.x;
  int idx = blockIdx.x * 256 + tid;
  float bar = 0.f;
  if (idx < NT) bar = frv[mrec[idx]] - sDV[idx];
  for (int off = 32; off >= 1; off >>= 1) bar = fmaxf(bar, __shfl_down(bar, off));
  if ((tid & 63) == 0) lm[tid >> 6] = bar;
  __syncthreads();
  if (tid == 0) {
    float m = fmaxf(fmaxf(lm[0], lm[1]), fmaxf(lm[2], lm[3]));
    atomicMax(&accU[5], fmap(m));
  }
}

// ---------------- K8: assemble output ----------------
__global__ void k_out(const float* __restrict__ accF, const u32* __restrict__ accU, float* out) {
  float loss0 = accF[0] + accF[1] - funmap(accU[2]);
  float sum1 = accF[3] - accF[4];
  float max1 = funmap(accU[5]);
  out[0] = loss0 + sum1 - max1;
}

extern "C" void kernel_launch(void* const* d_in, const int* in_sizes, int n_in,
                              void* d_out, int out_size, void* d_ws, size_t ws_size,
                              hipStream_t stream) {
  const float* beta = (const float*)d_in[0];
  float* out = (float*)d_out;
  char* ws = (char*)d_ws;
  float* accF = (float*)(ws + OFF_ACC);
  u32*   accU = (u32*)(ws + OFF_ACC);
  u32*   gtmp = (u32*)(ws + OFF_ACC + 64);
  u32* r32 = (u32*)(ws + OFF_R32);
  u32* frk = (u32*)(ws + OFF_FRK);
  float* fval = (float*)(ws + OFF_FVAL);
  float* frv = (float*)(ws + OFF_FRV);
  float* dvals = (float*)(ws + OFF_DVAL);
  u32* epP = (u32*)(ws + OFF_EPP);
  u32* epD = (u32*)(ws + OFF_EPD);
  uint2* lPA = (uint2*)(ws + OFF_LPA);
  uint2* lPB = (uint2*)(ws + OFF_LPB);
  uint2* lDA = (uint2*)(ws + OFF_LDA);
  uint2* lDB = (uint2*)(ws + OFF_LDB);
  u32* treeKey = (u32*)(ws + OFF_TKEY);
  u32* treeAB = (u32*)(ws + OFF_TAB);     // reused as mrec by k_pair/k_final
  float* treeDV = (float*)(ws + OFF_TDV);
  u32* sRK = (u32*)(ws + OFF_SRK);
  float* sDV = (float*)(ws + OFF_SDV);
  u32* candP = (u32*)(ws + OFF_CANDP);
  u32* candD = (u32*)(ws + OFF_CANDD);
  u32* mrec = treeAB;

  hipLaunchKernelGGL(k_init, dim3(127), dim3(256), 0, stream, accF, accU, r32, frk);
  hipLaunchKernelGGL(k_build, dim3(191), dim3(256), 0, stream, beta, fval, accF, accU);
  hipLaunchKernelGGL(k_rankv, dim3(64, 16), dim3(256), 0, stream, beta, r32);
  hipLaunchKernelGGL(k_rankf, dim3(127, 8), dim3(256), 0, stream, fval, frk);
  hipLaunchKernelGGL(k_scatf, dim3(127), dim3(256), 0, stream, fval, frk, frv);
  hipLaunchKernelGGL(k_edges, dim3(191), dim3(256), 0, stream, beta, r32, dvals, epP, epD, lPA, lDA);
  hipLaunchKernelGGL(k_boruvka, dim3(2), dim3(1024), 0, stream, dvals, epP, epD,
                     lPA, lPB, lDA, lDB, candP, candD, treeKey, treeAB, treeDV, accF);
  hipLaunchKernelGGL(k_sorttree, dim3(1), dim3(1024), 0, stream, treeKey, treeAB, treeDV, frk, sRK, sDV, gtmp);
  hipLaunchKernelGGL(k_pair, dim3(1), dim3(1024), 0, stream, sRK, mrec);
  hipLaunchKernelGGL(k_final, dim3(127), dim3(256), 0, stream, mrec, sDV, frv, accU);
  hipLaunchKernelGGL(k_out, dim3(1), dim3(1), 0, stream, accF, accU, out);
}

// Round 4
// 992.116 us; speedup vs baseline: 4.4344x; 4.1033x over previous
//
#include <hip/hip_runtime.h>

#define NV 16384
#define EH 16256
#define EVV 16256
#define ED 16129
#define NE 48641
#define NT 32258
#define ND 32259
#define OUTERF 32258

typedef unsigned int u32;
typedef unsigned short u16;

// ---------------- ws layout ----------------
static __host__ __device__ constexpr size_t al256(size_t x) { return (x + 255) & ~(size_t)255; }
static constexpr size_t OFF_ACC   = 0;
static constexpr size_t OFF_R32   = 256;
static constexpr size_t OFF_FRK   = OFF_R32   + al256(NV * 4);
static constexpr size_t OFF_FVAL  = OFF_FRK   + al256(ND * 4);
static constexpr size_t OFF_FRV   = OFF_FVAL  + al256(ND * 4);
static constexpr size_t OFF_DVAL  = OFF_FRV   + al256(ND * 4);
static constexpr size_t OFF_EPP   = OFF_DVAL  + al256(NE * 4);
static constexpr size_t OFF_EPD   = OFF_EPP   + al256(NE * 4);
static constexpr size_t OFF_LPA   = OFF_EPD   + al256(NE * 4);
static constexpr size_t OFF_LPB   = OFF_LPA   + al256(NE * 8);
static constexpr size_t OFF_LDA   = OFF_LPB   + al256(NE * 8);
static constexpr size_t OFF_LDB   = OFF_LDA   + al256(NE * 8);
static constexpr size_t OFF_TKEY  = OFF_LDB   + al256(NE * 8);
static constexpr size_t OFF_TAB   = OFF_TKEY  + al256(NT * 4);   // reused as mrec by k_pair
static constexpr size_t OFF_TDV   = OFF_TAB   + al256(NT * 4);
static constexpr size_t OFF_SRK   = OFF_TDV   + al256(NT * 4);   // sorted rank-pairs
static constexpr size_t OFF_SDV   = OFF_SRK   + al256(NT * 4);
static constexpr size_t OFF_CANDP = OFF_SDV   + al256(NT * 4);
static constexpr size_t OFF_CANDD = OFF_CANDP + al256(NV * 4);
static constexpr size_t OFF_MTAB  = OFF_CANDD + al256(NV * 4);   // u32[ND+1]
static constexpr size_t OFF_TMP   = OFF_MTAB  + al256((ND + 1) * 4);
static constexpr size_t OFF_REMA  = OFF_TMP   + al256(NT * 4);
static constexpr size_t OFF_REMB  = OFF_REMA  + al256(NT * 4);

__device__ __forceinline__ u32 fmap(float x) {
  u32 u = __float_as_uint(x);
  return (u & 0x80000000u) ? ~u : (u | 0x80000000u);
}
__device__ __forceinline__ float funmap(u32 m) {
  u32 u = (m & 0x80000000u) ? (m & 0x7FFFFFFFu) : ~m;
  return __uint_as_float(u);
}

__device__ __forceinline__ int findh(volatile u16* par, int x) {
  while (true) {
    int p = par[x];
    if (p == x) return x;
    int gp = par[p];
    if (gp == p) return p;
    par[x] = (u16)gp;
    x = gp;
  }
}

// ---------------- K0: init ----------------
// acc: F[0]=primal MST wsum, F[1]=sum beta, U[2]=max beta(fmap),
//      F[3]=sum fval(faces), F[4]=sum dv(dual tree), U[5]=max bar(fmap)
__global__ void k_init(float* accF, u32* accU, u32* r32, u32* frk, u32* mtab) {
  int i = blockIdx.x * 256 + threadIdx.x;
  if (i < 6) accF[i] = 0.f;
  if (i < NV) r32[i] = 0u;
  if (i < ND) frk[i] = 0u;
  if (i < ND + 1) mtab[i] = 0xFFFFFFFFu;
}

// ---------------- K1: face values + reductions ----------------
__global__ void k_build(const float* __restrict__ beta, float* fval, float* accF, u32* accU) {
  __shared__ float ls[4], lm[4];
  int bid = blockIdx.x, tid = threadIdx.x;
  if (bid < 64) {
    int v = (bid << 8) + tid;
    float b = beta[v];
    float s = b, m = b;
    for (int off = 32; off >= 1; off >>= 1) {
      s += __shfl_down(s, off);
      m = fmaxf(m, __shfl_down(m, off));
    }
    int wid = tid >> 6;
    if ((tid & 63) == 0) { ls[wid] = s; lm[wid] = m; }
    __syncthreads();
    if (tid == 0) {
      s = ls[0] + ls[1] + ls[2] + ls[3];
      m = fmaxf(fmaxf(lm[0], lm[1]), fmaxf(lm[2], lm[3]));
      atomicAdd(&accF[1], s);
      atomicMax(&accU[2], fmap(m));
    }
  } else {
    int t = ((bid - 64) << 8) + tid;
    float c = 0.f;
    if (t < NT) {
      int i, j, v0; float fv;
      if (t < ED) { i = t / 127; j = t - i * 127; v0 = (i << 7) + j;
        fv = fminf(fminf(beta[v0], beta[v0 + 128]), beta[v0 + 129]); }  // L(i,j)
      else { int u = t - ED; i = u / 127; j = u - i * 127; v0 = (i << 7) + j;
        fv = fminf(fminf(beta[v0], beta[v0 + 1]), beta[v0 + 129]); }    // U(i,j)
      c = -fv;
      fval[t] = -fv;
      if (t == 0) fval[OUTERF] = __builtin_inff();
    }
    for (int off = 32; off >= 1; off >>= 1) c += __shfl_down(c, off);
    int wid = tid >> 6;
    if ((tid & 63) == 0) ls[wid] = c;
    __syncthreads();
    if (tid == 0) atomicAdd(&accF[3], ls[0] + ls[1] + ls[2] + ls[3]);
  }
}

// ---------------- K2v: vertex ranks ----------------
__global__ void k_rankv(const float* __restrict__ beta, u32* r32) {
  int v = blockIdx.x * 256 + threadIdx.x;
  int c = blockIdx.y;
  float bv = beta[v];
  int u0 = c << 10;
  int cnt = 0;
#pragma unroll 8
  for (int u = u0; u < u0 + 1024; ++u) {
    float bu = beta[u];
    cnt += (bu < bv || (bu == bv && u < v)) ? 1 : 0;
  }
  if (cnt) atomicAdd(&r32[v], (u32)cnt);
}

// ---------------- K2f: face ranks (descending fval, id tiebreak) ----------------
__global__ void k_rankf(const float* __restrict__ fval, u32* frk) {
  int g = blockIdx.x * 256 + threadIdx.x;
  if (g >= ND) return;
  float fg = fval[g];
  int u0 = blockIdx.y * 4033;
  int u1 = min(u0 + 4033, ND);
  int cnt = 0;
#pragma unroll 8
  for (int u = u0; u < u1; ++u) {
    float fu = fval[u];
    cnt += (fu > fg || (fu == fg && u < g)) ? 1 : 0;
  }
  if (cnt) atomicAdd(&frk[g], (u32)cnt);
}

// ---------------- K2b: scatter rank->value ----------------
__global__ void k_scatf(const float* __restrict__ fval, const u32* __restrict__ frk, float* frv) {
  int g = blockIdx.x * 256 + threadIdx.x;
  if (g < ND) frv[frk[g]] = fval[g];
}

// ---------------- K3: build edges ----------------
__global__ void k_edges(const float* __restrict__ beta, const u32* __restrict__ r32,
                        float* dvals, u32* epP, u32* epD, uint2* listP, uint2* listD) {
  int e = blockIdx.x * 256 + threadIdx.x;
  if (e >= NE) return;
  int eu, ev, fa, fb;
  if (e < EH) {
    int i = e / 127, j = e - (e / 127) * 127;
    eu = (i << 7) + j; ev = eu + 1;
    fa = (i < 127) ? (ED + i * 127 + j) : OUTERF;
    fb = (i >= 1) ? ((i - 1) * 127 + j) : OUTERF;
  } else if (e < EH + EVV) {
    int k = e - EH;
    int i = k >> 7, j = k & 127;
    eu = (i << 7) + j; ev = eu + 128;
    fa = (j < 127) ? (i * 127 + j) : OUTERF;
    fb = (j >= 1) ? (ED + i * 127 + (j - 1)) : OUTERF;
  } else {
    int k = e - EH - EVV;
    int i = k / 127, j = k - (k / 127) * 127;
    eu = (i << 7) + j; ev = eu + 129;
    fa = i * 127 + j; fb = ED + i * 127 + j;
  }
  float bu = beta[eu], bv = beta[ev];
  float dv = -fminf(bu, bv);
  int cv = (bu <= bv) ? eu : ev;
  u32 rr = r32[cv];
  dvals[e] = dv;
  u32 pp = (u32)eu | ((u32)ev << 16);
  u32 dd = (u32)fa | ((u32)fb << 16);
  epP[e] = pp;
  epD[e] = dd;
  listP[e] = make_uint2(((16383u - rr) << 17) | (u32)e, pp);
  listD[e] = make_uint2((rr << 17) | (u32)e, dd);
}

// ---------------- K4: Boruvka ----------------
__global__ __launch_bounds__(1024) void k_boruvka(
    const float* __restrict__ dvals, const u32* __restrict__ epP, const u32* __restrict__ epD,
    uint2* lPA, uint2* lPB, uint2* lDA, uint2* lDB,
    u32* candP, u32* candD,
    u32* treeKey, u32* treeAB, float* treeDV, float* accF) {
  const bool dual = (blockIdx.x != 0);
  const int Nn = dual ? ND : NV;
  const u32* ep = dual ? epD : epP;
  u32* cand = dual ? candD : candP;
  uint2* listA = dual ? lDA : lPA;
  uint2* listB = dual ? lDB : lPB;
  __shared__ u16 par[ND];
  __shared__ int nCur, nNxt, treeCnt, changed;
  __shared__ float wred[16];
  int tid = threadIdx.x;
  for (int v = tid; v < Nn; v += 1024) { par[v] = (u16)v; cand[v] = 0xFFFFFFFFu; }
  if (tid == 0) { nCur = NE; treeCnt = 0; }
  float wloc = 0.f;
  __syncthreads();
  for (int round = 0; round < 40; ++round) {
    uint2* cur = (round & 1) ? listB : listA;
    uint2* nxt = (round & 1) ? listA : listB;
    if (tid == 0) nNxt = 0;
    __syncthreads();
    int n = nCur;
    for (int i = tid; i < n; i += 1024) {
      uint2 rec = cur[i];
      int a = (int)(rec.y & 0xFFFFu), b = (int)(rec.y >> 16);
      int ra = findh((volatile u16*)par, a);
      int rb = findh((volatile u16*)par, b);
      if (ra != rb) {
        int pos = atomicAdd(&nNxt, 1);
        nxt[pos] = make_uint2(rec.x, (u32)ra | ((u32)rb << 16));
        atomicMin(&cand[ra], rec.x);
        atomicMin(&cand[rb], rec.x);
      }
    }
    __syncthreads();
    u32 hooks[32];
#pragma unroll
    for (int it = 0; it < 32; ++it) {
      hooks[it] = 0xFFFFFFFFu;
      int v = tid + (it << 10);
      if (v < Nn) {
        u32 c = ((volatile u32*)cand)[v];
        if (c != 0xFFFFFFFFu && par[v] == (u16)v) {
          int eid = (int)(c & 0x1FFFFu);
          u32 ab = ep[eid];
          int ea = (int)(ab & 0xFFFFu), eb = (int)(ab >> 16);
          int ra = findh((volatile u16*)par, ea);
          int rb = findh((volatile u16*)par, eb);
          int w = (ra == v) ? rb : ra;
          u32 cw = ((volatile u32*)cand)[w];
          bool mutual = (cw != 0xFFFFFFFFu) && ((int)(cw & 0x1FFFFu) == eid);
          if (!mutual || v < w) {
            hooks[it] = (u32)w;
            if (dual) {
              int pos = atomicAdd(&treeCnt, 1);
              treeKey[pos] = c; treeAB[pos] = ab;
              treeDV[pos] = dvals[eid];
              wloc += dvals[eid];
            } else {
              atomicAdd(&treeCnt, 1);
              wloc += dvals[eid];
            }
          }
        }
      }
    }
    __syncthreads();
#pragma unroll
    for (int it = 0; it < 32; ++it) {
      int v = tid + (it << 10);
      if (v < Nn && hooks[it] != 0xFFFFFFFFu) par[v] = (u16)hooks[it];
    }
    __syncthreads();
    for (int jr = 0; jr < 24; ++jr) {
      if (tid == 0) changed = 0;
      __syncthreads();
      for (int v = tid; v < Nn; v += 1024) {
        int p = par[v]; int pp = par[p];
        if (p != pp) { par[v] = (u16)pp; changed = 1; }
      }
      __syncthreads();
      if (!changed) break;
    }
    __syncthreads();
    if (tid == 0) nCur = nNxt;
    __syncthreads();
    if (treeCnt >= Nn - 1 || nCur == 0) break;
    for (int v = tid; v < Nn; v += 1024) cand[v] = 0xFFFFFFFFu;
    __syncthreads();
  }
  for (int off = 32; off >= 1; off >>= 1) wloc += __shfl_down(wloc, off);
  if ((tid & 63) == 0) wred[tid >> 6] = wloc;
  __syncthreads();
  if (tid == 0) {
    float s = 0.f;
    for (int w = 0; w < 16; ++w) s += wred[w];
    atomicAdd(&accF[dual ? 4 : 0], s);
  }
}

// ---------------- K5: counting-sort dual tree edges by rank, map to rank-space ----------------
__global__ __launch_bounds__(1024) void k_sorttree(
    const u32* __restrict__ treeKey, const u32* __restrict__ treeAB, const float* __restrict__ treeDV,
    const u32* __restrict__ frk, u32* sRK, float* sDV, u32* gtmp) {
  __shared__ u32 cnt[NV];
  int tid = threadIdx.x;
  for (int b = tid; b < NV; b += 1024) cnt[b] = 0u;
  __syncthreads();
  for (int t = tid; t < NT; t += 1024) atomicAdd(&cnt[treeKey[t] >> 17], 1u);
  __syncthreads();
  u32 loc[16]; u32 s = 0;
#pragma unroll
  for (int k = 0; k < 16; ++k) { loc[k] = s; s += cnt[(tid << 4) + k]; }
  int lane = tid & 63, wid = tid >> 6;
  u32 incl = s;
  for (int off = 1; off < 64; off <<= 1) {
    u32 o = __shfl_up(incl, off);
    if (lane >= off) incl += o;
  }
  if (lane == 63) gtmp[wid] = incl;
  __syncthreads();
  u32 wbase = 0;
  for (int w = 0; w < 16; ++w) { u32 tt = gtmp[w]; wbase += (w < wid) ? tt : 0u; }
  u32 base = wbase + incl - s;
#pragma unroll
  for (int k = 0; k < 16; ++k) cnt[(tid << 4) + k] = base + loc[k];
  __syncthreads();
  for (int t = tid; t < NT; t += 1024) {
    u32 key = treeKey[t];
    u32 ab = treeAB[t];
    u32 pos = atomicAdd(&cnt[key >> 17], 1u);
    sRK[pos] = frk[ab & 0xFFFFu] | (frk[ab >> 16] << 16);
    sDV[pos] = treeDV[t];
  }
}

// ---------------- K6: fully-parallel exact Kruskal pairing ----------------
// Rank-space: root label == min rank (oldest face) of component; edge index == time.
// Per round: (P1) all remaining edges find roots, atomicMin edge-index into
// mtab[youngerRoot]; (P2) edge commits iff it is mtab[y] — then record mrec=y and
// hook par[y]=o. Exactness: only an earlier edge whose YOUNGER root is also y could
// change y's component label before time k; commit condition excludes exactly that.
// The minimum remaining edge always commits => guaranteed progress.
__global__ __launch_bounds__(1024) void k_pair(
    const u32* __restrict__ sRK, u32* __restrict__ mrec,
    u32* __restrict__ mtab, u32* __restrict__ tmp,
    u32* __restrict__ remA, u32* __restrict__ remB) {
  __shared__ u16 par[ND + 1];
  __shared__ int nRem, nNxt;
  int tid = threadIdx.x;
  {
    u32* p32 = (u32*)par;
    for (int v = tid; v < (ND + 1) / 2; v += 1024)
      p32[v] = ((2u * v + 1) << 16) | (2u * v);
  }
  if (tid == 0) nRem = NT;
  __syncthreads();
  u32* remCur = remA;
  u32* remNxt = remB;
  for (int round = 0; round < NT + 8; ++round) {
    int R = nRem;
    if (R == 0) break;
    if (tid == 0) nNxt = 0;
    // ---- P1: parallel find + claim ----
    for (int i = tid; i < R; i += 1024) {
      u32 e = (round == 0) ? (u32)i : remCur[i];
      u32 ab = sRK[e];
      int ra = findh((volatile u16*)par, (int)(ab & 0xFFFFu));
      int rb = findh((volatile u16*)par, (int)(ab >> 16));
      u32 y = (u32)max(ra, rb), o = (u32)min(ra, rb);
      tmp[i] = (y << 16) | o;
      atomicMin(&mtab[y], e);
    }
    __syncthreads();
    // ---- P2: commit winners, survivors to next list ----
    for (int i = tid; i < R; i += 1024) {
      u32 e = (round == 0) ? (u32)i : remCur[i];
      u32 t = tmp[i];
      u32 y = t >> 16, o = t & 0xFFFFu;
      if (mtab[y] == e) {
        mrec[e] = y;
        par[y] = (u16)o;
      } else {
        int pos = atomicAdd(&nNxt, 1);
        remNxt[pos] = e;
      }
    }
    __syncthreads();
    // ---- P3: reset touched mtab entries + compress ----
    for (int i = tid; i < R; i += 1024) mtab[tmp[i] >> 16] = 0xFFFFFFFFu;
    for (int v = tid; v < ND; v += 1024) {
      int p = par[v]; int pp = par[p];
      if (p != pp) par[v] = (u16)pp;
    }
    __syncthreads();
    if (tid == 0) nRem = nNxt;
    __syncthreads();
    u32* s = remCur; remCur = remNxt; remNxt = s;
  }
}

// ---------------- K7: max bar reduction ----------------
__global__ void k_final(const u32* __restrict__ mrec, const float* __restrict__ sDV,
                        const float* __restrict__ frv, u32* accU) {
  __shared__ float lm[4];
  int tid = threadIdx.x;
  int idx = blockIdx.x * 256 + tid;
  float bar = 0.f;
  if (idx < NT) bar = frv[mrec[idx]] - sDV[idx];
  for (int off = 32; off >= 1; off >>= 1) bar = fmaxf(bar, __shfl_down(bar, off));
  if ((tid & 63) == 0) lm[tid >> 6] = bar;
  __syncthreads();
  if (tid == 0) {
    float m = fmaxf(fmaxf(lm[0], lm[1]), fmaxf(lm[2], lm[3]));
    atomicMax(&accU[5], fmap(m));
  }
}

// ---------------- K8: assemble output ----------------
__global__ void k_out(const float* __restrict__ accF, const u32* __restrict__ accU, float* out) {
  float loss0 = accF[0] + accF[1] - funmap(accU[2]);
  float sum1 = accF[3] - accF[4];
  float max1 = funmap(accU[5]);
  out[0] = loss0 + sum1 - max1;
}

extern "C" void kernel_launch(void* const* d_in, const int* in_sizes, int n_in,
                              void* d_out, int out_size, void* d_ws, size_t ws_size,
                              hipStream_t stream) {
  const float* beta = (const float*)d_in[0];
  float* out = (float*)d_out;
  char* ws = (char*)d_ws;
  float* accF = (float*)(ws + OFF_ACC);
  u32*   accU = (u32*)(ws + OFF_ACC);
  u32*   gtmp = (u32*)(ws + OFF_ACC + 64);
  u32* r32 = (u32*)(ws + OFF_R32);
  u32* frk = (u32*)(ws + OFF_FRK);
  float* fval = (float*)(ws + OFF_FVAL);
  float* frv = (float*)(ws + OFF_FRV);
  float* dvals = (float*)(ws + OFF_DVAL);
  u32* epP = (u32*)(ws + OFF_EPP);
  u32* epD = (u32*)(ws + OFF_EPD);
  uint2* lPA = (uint2*)(ws + OFF_LPA);
  uint2* lPB = (uint2*)(ws + OFF_LPB);
  uint2* lDA = (uint2*)(ws + OFF_LDA);
  uint2* lDB = (uint2*)(ws + OFF_LDB);
  u32* treeKey = (u32*)(ws + OFF_TKEY);
  u32* treeAB = (u32*)(ws + OFF_TAB);     // reused as mrec by k_pair/k_final
  float* treeDV = (float*)(ws + OFF_TDV);
  u32* sRK = (u32*)(ws + OFF_SRK);
  float* sDV = (float*)(ws + OFF_SDV);
  u32* candP = (u32*)(ws + OFF_CANDP);
  u32* candD = (u32*)(ws + OFF_CANDD);
  u32* mtab = (u32*)(ws + OFF_MTAB);
  u32* tmp  = (u32*)(ws + OFF_TMP);
  u32* remA = (u32*)(ws + OFF_REMA);
  u32* remB = (u32*)(ws + OFF_REMB);
  u32* mrec = treeAB;

  hipLaunchKernelGGL(k_init, dim3(127), dim3(256), 0, stream, accF, accU, r32, frk, mtab);
  hipLaunchKernelGGL(k_build, dim3(191), dim3(256), 0, stream, beta, fval, accF, accU);
  hipLaunchKernelGGL(k_rankv, dim3(64, 16), dim3(256), 0, stream, beta, r32);
  hipLaunchKernelGGL(k_rankf, dim3(127, 8), dim3(256), 0, stream, fval, frk);
  hipLaunchKernelGGL(k_scatf, dim3(127), dim3(256), 0, stream, fval, frk, frv);
  hipLaunchKernelGGL(k_edges, dim3(191), dim3(256), 0, stream, beta, r32, dvals, epP, epD, lPA, lDA);
  hipLaunchKernelGGL(k_boruvka, dim3(2), dim3(1024), 0, stream, dvals, epP, epD,
                     lPA, lPB, lDA, lDB, candP, candD, treeKey, treeAB, treeDV, accF);
  hipLaunchKernelGGL(k_sorttree, dim3(1), dim3(1024), 0, stream, treeKey, treeAB, treeDV, frk, sRK, sDV, gtmp);
  hipLaunchKernelGGL(k_pair, dim3(1), dim3(1024), 0, stream, sRK, mrec, mtab, tmp, remA, remB);
  hipLaunchKernelGGL(k_final, dim3(127), dim3(256), 0, stream, mrec, sDV, frv, accU);
  hipLaunchKernelGGL(k_out, dim3(1), dim3(1), 0, stream, accF, accU, out);
}

// Round 5
// 590.188 us; speedup vs baseline: 7.4544x; 1.6810x over previous
//
#include <hip/hip_runtime.h>

#define NV 16384
#define EH 16256
#define EVV 16256
#define ED 16129
#define NE 48641
#define NT 32258
#define ND 32259
#define OUTERF 32258

typedef unsigned int u32;
typedef unsigned short u16;

// ---------------- ws layout ----------------
static __host__ __device__ constexpr size_t al256(size_t x) { return (x + 255) & ~(size_t)255; }
static constexpr size_t OFF_ACC   = 0;                                  // acc[0..6), gtmp at +64
static constexpr size_t OFF_R32   = 256;
static constexpr size_t OFF_FVAL  = OFF_R32   + al256(NV * 4);
static constexpr size_t OFF_CTV   = OFF_FVAL  + al256(ND * 4);          // u16[NT]
static constexpr size_t OFF_CNTR  = OFF_CTV   + al256(NT * 2);          // u32[NV] -> in-place scan -> starts
static constexpr size_t OFF_FRK   = OFF_CNTR  + al256(NV * 4);          // u32[ND]
static constexpr size_t OFF_FRV   = OFF_FRK   + al256(ND * 4);          // f32[ND]
static constexpr size_t OFF_DVAL  = OFF_FRV   + al256(ND * 4);          // f32[NE]
static constexpr size_t OFF_LA    = OFF_DVAL  + al256(NE * 4);          // uint2[NE]
static constexpr size_t OFF_LB    = OFF_LA    + al256(NE * 8);          // uint2[NE]
static constexpr size_t OFF_TMP   = OFF_LB    + al256(NE * 8);          // u32[NE]
static constexpr size_t OFF_MTAB  = OFF_TMP   + al256(NE * 4);          // u32[ND+1]
static constexpr size_t OFF_TKEY  = OFF_MTAB  + al256((ND + 1) * 4);    // u32[NT]
static constexpr size_t OFF_TRK   = OFF_TKEY  + al256(NT * 4);          // u32[NT] (reused as mrec)
static constexpr size_t OFF_TDV   = OFF_TRK   + al256(NT * 4);          // f32[NT]
static constexpr size_t OFF_SRK   = OFF_TDV   + al256(NT * 4);          // u32[NT]
static constexpr size_t OFF_SDV   = OFF_SRK   + al256(NT * 4);          // f32[NT]
static constexpr size_t OFF_REMA  = OFF_SDV   + al256(NT * 4);          // u32[NT]
static constexpr size_t OFF_REMB  = OFF_REMA  + al256(NT * 4);          // u32[NT]

__device__ __forceinline__ u32 fmap(float x) {
  u32 u = __float_as_uint(x);
  return (u & 0x80000000u) ? ~u : (u | 0x80000000u);
}
__device__ __forceinline__ float funmap(u32 m) {
  u32 u = (m & 0x80000000u) ? (m & 0x7FFFFFFFu) : ~m;
  return __uint_as_float(u);
}

__device__ __forceinline__ int findh(volatile u16* par, int x) {
  while (true) {
    int p = par[x];
    if (p == x) return x;
    int gp = par[p];
    if (gp == p) return p;
    par[x] = (u16)gp;
    x = gp;
  }
}

// ---------------- K0: init ----------------
// acc: F[0]=sum dv(all edges), F[1]=sum beta, U[2]=max beta(fmap),
//      F[3]=sum fval(faces), F[4]=sum dv(dual maxST), U[5]=max bar(fmap)
__global__ void k_init(float* accF, u32* r32, u32* mtab) {
  int i = blockIdx.x * 256 + threadIdx.x;
  if (i < 6) accF[i] = 0.f;
  if (i < NV) r32[i] = 0u;
  if (i < ND + 1) mtab[i] = 0xFFFFFFFFu;
}

// ---------------- K1: vertex ranks (ascending beta, id tiebreak) ----------------
__global__ void k_rankv(const float* __restrict__ beta, u32* r32) {
  int v = blockIdx.x * 256 + threadIdx.x;
  int c = blockIdx.y;
  float bv = beta[v];
  int u0 = c << 10;
  int cnt = 0;
#pragma unroll 8
  for (int u = u0; u < u0 + 1024; ++u) {
    float bu = beta[u];
    cnt += (bu < bv || (bu == bv && u < v)) ? 1 : 0;
  }
  if (cnt) atomicAdd(&r32[v], (u32)cnt);
}

// ---------------- K2: face values + crit vertex + reductions ----------------
__global__ void k_build(const float* __restrict__ beta, const u32* __restrict__ r32,
                        float* fval, u16* ctv, float* accF, u32* accU) {
  __shared__ float ls[4], lm[4];
  int bid = blockIdx.x, tid = threadIdx.x;
  if (bid < 64) {
    int v = (bid << 8) + tid;
    float b = beta[v];
    float s = b, m = b;
    for (int off = 32; off >= 1; off >>= 1) {
      s += __shfl_down(s, off);
      m = fmaxf(m, __shfl_down(m, off));
    }
    int wid = tid >> 6;
    if ((tid & 63) == 0) { ls[wid] = s; lm[wid] = m; }
    __syncthreads();
    if (tid == 0) {
      s = ls[0] + ls[1] + ls[2] + ls[3];
      m = fmaxf(fmaxf(lm[0], lm[1]), fmaxf(lm[2], lm[3]));
      atomicAdd(&accF[1], s);
      atomicMax(&accU[2], fmap(m));
    }
  } else {
    int t = ((bid - 64) << 8) + tid;
    float c = 0.f;
    if (t < NT) {
      int i, j, v0, v1, v2;
      if (t < ED) { i = t / 127; j = t - i * 127; v0 = (i << 7) + j; v1 = v0 + 128; v2 = v0 + 129; } // L
      else { int u = t - ED; i = u / 127; j = u - i * 127; v0 = (i << 7) + j; v1 = v0 + 1; v2 = v0 + 129; } // U
      u32 r0 = r32[v0], r1 = r32[v1], r2 = r32[v2];
      int crit = v0; u32 rm = r0;
      if (r1 < rm) { rm = r1; crit = v1; }
      if (r2 < rm) { rm = r2; crit = v2; }
      float fv = -beta[crit];          // = -min beta over corners (r32 monotone in (beta,id))
      fval[t] = fv;
      ctv[t] = (u16)crit;
      c = fv;
      if (t == 0) fval[OUTERF] = __builtin_inff();
    }
    for (int off = 32; off >= 1; off >>= 1) c += __shfl_down(c, off);
    int wid = tid >> 6;
    if ((tid & 63) == 0) ls[wid] = c;
    __syncthreads();
    if (tid == 0) atomicAdd(&accF[3], ls[0] + ls[1] + ls[2] + ls[3]);
  }
}

// ---------------- K3a: per-vertex crit-face counts into rank buckets ----------------
__global__ void k_cntface(const u16* __restrict__ ctv, const u32* __restrict__ r32, u32* cntR) {
  int v = blockIdx.x * 256 + threadIdx.x;   // 64 blocks x 256 = NV
  int i = v >> 7, j = v & 127;
  int cnt = 0;
  if (i < 127 && j < 127) cnt += (ctv[i * 127 + j] == v);
  if (i >= 1 && j < 127)  cnt += (ctv[(i - 1) * 127 + j] == v);
  if (i >= 1 && j >= 1)   cnt += (ctv[(i - 1) * 127 + (j - 1)] == v);
  if (i < 127 && j < 127) cnt += (ctv[ED + i * 127 + j] == v);
  if (i < 127 && j >= 1)  cnt += (ctv[ED + i * 127 + (j - 1)] == v);
  if (i >= 1 && j >= 1)   cnt += (ctv[ED + (i - 1) * 127 + (j - 1)] == v);
  cntR[r32[v]] = (u32)cnt;
}

// ---------------- K3b: exclusive prefix scan over NV rank buckets (+1 for outer face rank 0) ----------------
__global__ __launch_bounds__(1024) void k_scanR(u32* cntR) {
  __shared__ u32 wsum[16];
  int tid = threadIdx.x;
  u32 loc[16]; u32 s = 0;
#pragma unroll
  for (int k = 0; k < 16; ++k) { u32 c = cntR[(tid << 4) + k]; loc[k] = s; s += c; }
  int lane = tid & 63, wid = tid >> 6;
  u32 incl = s;
  for (int off = 1; off < 64; off <<= 1) {
    u32 o = __shfl_up(incl, off);
    if (lane >= off) incl += o;
  }
  if (lane == 63) wsum[wid] = incl;
  __syncthreads();
  u32 wbase = 0;
  for (int w = 0; w < wid; ++w) wbase += wsum[w];
  u32 base = wbase + incl - s + 1;   // +1: rank 0 reserved for outer face
#pragma unroll
  for (int k = 0; k < 16; ++k) cntR[(tid << 4) + k] = base + loc[k];
}

// ---------------- K3c: face ranks + rank->value table ----------------
__global__ void k_facerank(const u16* __restrict__ ctv, const u32* __restrict__ r32,
                           const u32* __restrict__ startsR, const float* __restrict__ fval,
                           u32* frk, float* frv) {
  int g = blockIdx.x * 256 + threadIdx.x;
  if (g == 0) { frk[OUTERF] = 0u; frv[0] = __builtin_inff(); }
  if (g >= NT) return;
  int v = ctv[g];
  int i = v >> 7, j = v & 127;
  int local = 0, f;
  if (i < 127 && j < 127) { f = i * 127 + j;             local += (f < g && ctv[f] == v); }
  if (i >= 1 && j < 127)  { f = (i - 1) * 127 + j;       local += (f < g && ctv[f] == v); }
  if (i >= 1 && j >= 1)   { f = (i - 1) * 127 + (j - 1); local += (f < g && ctv[f] == v); }
  if (i < 127 && j < 127) { f = ED + i * 127 + j;        local += (f < g && ctv[f] == v); }
  if (i < 127 && j >= 1)  { f = ED + i * 127 + (j - 1);  local += (f < g && ctv[f] == v); }
  if (i >= 1 && j >= 1)   { f = ED + (i - 1) * 127 + (j - 1); local += (f < g && ctv[f] == v); }
  u32 rk = startsR[r32[v]] + (u32)local;
  frk[g] = rk;
  frv[rk] = fval[g];
}

// ---------------- K4: build dual edges + sum of all edge values ----------------
__global__ void k_edges(const float* __restrict__ beta, const u32* __restrict__ r32,
                        float* dvals, uint2* listA, float* accF) {
  int e = blockIdx.x * 256 + threadIdx.x;
  float dv = 0.f;
  if (e < NE) {
    int eu, ev, fa, fb;
    if (e < EH) {                        // horizontal (i,j)-(i,j+1)
      int i = e / 127, j = e - (e / 127) * 127;
      eu = (i << 7) + j; ev = eu + 1;
      fa = (i < 127) ? (ED + i * 127 + j) : OUTERF;
      fb = (i >= 1) ? ((i - 1) * 127 + j) : OUTERF;
    } else if (e < EH + EVV) {           // vertical (i,j)-(i+1,j)
      int k = e - EH;
      int i = k >> 7, j = k & 127;
      eu = (i << 7) + j; ev = eu + 128;
      fa = (j < 127) ? (i * 127 + j) : OUTERF;
      fb = (j >= 1) ? (ED + i * 127 + (j - 1)) : OUTERF;
    } else {                             // diagonal (i,j)-(i+1,j+1)
      int k = e - EH - EVV;
      int i = k / 127, j = k - (k / 127) * 127;
      eu = (i << 7) + j; ev = eu + 129;
      fa = i * 127 + j; fb = ED + i * 127 + j;
    }
    u32 ru = r32[eu], rv = r32[ev];
    int cv; u32 rr;
    if (ru <= rv) { cv = eu; rr = ru; } else { cv = ev; rr = rv; }
    dv = -beta[cv];
    dvals[e] = dv;
    u32 key = (rr << 17) | (u32)e;       // dual maxST order: rank asc (f desc), eid tiebreak
    listA[e] = make_uint2(key, (u32)fa | ((u32)fb << 16));
  }
  float ds = dv;
  for (int off = 32; off >= 1; off >>= 1) ds += __shfl_down(ds, off);
  if ((threadIdx.x & 63) == 0) atomicAdd(&accF[0], ds);
}

// ---------------- K5: dual maxST via parallel claim-both-roots MST (ECL-style) ----------------
// Per round: pending edges find roots (LDS par); drop if equal; atomicMin key into
// mtab[ra], mtab[rb]. Winner of EITHER root commits (cut property: min pending edge
// crossing that component's cut => in unique MST) and hooks the root it won (unique
// winner per root => race-free; min-chain argument => no hook cycles). Drops safe:
// committed edges all in MST, so equal roots => cycle with MST edges => not in MST.
__global__ __launch_bounds__(1024) void k_mst(
    const float* __restrict__ dvals, uint2* lA, uint2* lB,
    u32* __restrict__ mtab, u32* __restrict__ tmp,
    const u32* __restrict__ frk,
    u32* treeKey, u32* treeRK, float* treeDV, float* accF) {
  __shared__ u16 par[ND];
  __shared__ int nCur, nNxt, treeCnt;
  __shared__ float wred[16];
  int tid = threadIdx.x;
  for (int v = tid; v < ND; v += 1024) par[v] = (u16)v;
  if (tid == 0) { nCur = NE; nNxt = 0; treeCnt = 0; }
  float wloc = 0.f;
  __syncthreads();
  uint2* cur = lA;
  uint2* nxt = lB;
  for (int round = 0; round < 30; ++round) {
    int n = nCur;
    if (n == 0) break;
    // P1: find + claim both roots
    for (int i = tid; i < n; i += 1024) {
      uint2 rec = cur[i];
      int fa = (int)(rec.y & 0xFFFFu), fb = (int)(rec.y >> 16);
      int ra = findh((volatile u16*)par, fa);
      int rb = findh((volatile u16*)par, fb);
      if (ra == rb) tmp[i] = 0xFFFFFFFFu;          // cycle edge: drop
      else {
        tmp[i] = (u32)ra | ((u32)rb << 16);
        atomicMin(&mtab[ra], rec.x);
        atomicMin(&mtab[rb], rec.x);
      }
    }
    __syncthreads();
    // P2: winners commit + hook; losers requeue
    for (int i = tid; i < n; i += 1024) {
      u32 t = tmp[i];
      if (t == 0xFFFFFFFFu) continue;
      uint2 rec = cur[i];
      int ra = (int)(t & 0xFFFFu), rb = (int)(t >> 16);
      bool wa = (mtab[ra] == rec.x), wb = (mtab[rb] == rec.x);
      if (wa | wb) {
        int pos = atomicAdd(&treeCnt, 1);
        treeKey[pos] = rec.x;
        treeRK[pos] = frk[rec.y & 0xFFFFu] | (frk[rec.y >> 16] << 16);
        float dv = dvals[rec.x & 0x1FFFFu];
        treeDV[pos] = dv;
        wloc += dv;
        if (wa && wb) { int y = max(ra, rb), o = min(ra, rb); par[y] = (u16)o; }
        else if (wa) par[ra] = (u16)rb;
        else par[rb] = (u16)ra;
      } else {
        int pos = atomicAdd(&nNxt, 1);
        nxt[pos] = rec;
      }
    }
    __syncthreads();
    // P3: reset touched mtab entries + one jump sweep
    for (int i = tid; i < n; i += 1024) {
      u32 t = tmp[i];
      if (t != 0xFFFFFFFFu) { mtab[t & 0xFFFFu] = 0xFFFFFFFFu; mtab[t >> 16] = 0xFFFFFFFFu; }
    }
    for (int v = tid; v < ND; v += 1024) {
      int p = par[v]; int pp = par[p];
      if (p != pp) par[v] = (u16)pp;
    }
    __syncthreads();
    if (tid == 0) { nCur = nNxt; nNxt = 0; }
    uint2* s = cur; cur = nxt; nxt = s;
    __syncthreads();
  }
  for (int off = 32; off >= 1; off >>= 1) wloc += __shfl_down(wloc, off);
  if ((tid & 63) == 0) wred[tid >> 6] = wloc;
  __syncthreads();
  if (tid == 0) {
    float s = 0.f;
    for (int w = 0; w < 16; ++w) s += wred[w];
    atomicAdd(&accF[4], s);
  }
}

// ---------------- K6: counting-sort dual tree edges by rank bucket ----------------
__global__ __launch_bounds__(1024) void k_sorttree(
    const u32* __restrict__ treeKey, const u32* __restrict__ treeRK, const float* __restrict__ treeDV,
    u32* sRK, float* sDV, u32* gtmp) {
  __shared__ u32 cnt[NV];
  int tid = threadIdx.x;
  for (int b = tid; b < NV; b += 1024) cnt[b] = 0u;
  __syncthreads();
  for (int t = tid; t < NT; t += 1024) atomicAdd(&cnt[treeKey[t] >> 17], 1u);
  __syncthreads();
  u32 loc[16]; u32 s = 0;
#pragma unroll
  for (int k = 0; k < 16; ++k) { loc[k] = s; s += cnt[(tid << 4) + k]; }
  int lane = tid & 63, wid = tid >> 6;
  u32 incl = s;
  for (int off = 1; off < 64; off <<= 1) {
    u32 o = __shfl_up(incl, off);
    if (lane >= off) incl += o;
  }
  if (lane == 63) gtmp[wid] = incl;
  __syncthreads();
  u32 wbase = 0;
  for (int w = 0; w < 16; ++w) { u32 tt = gtmp[w]; wbase += (w < wid) ? tt : 0u; }
  u32 base = wbase + incl - s;
#pragma unroll
  for (int k = 0; k < 16; ++k) cnt[(tid << 4) + k] = base + loc[k];
  __syncthreads();
  for (int t = tid; t < NT; t += 1024) {
    u32 key = treeKey[t];
    u32 pos = atomicAdd(&cnt[key >> 17], 1u);
    sRK[pos] = treeRK[t];
    sDV[pos] = treeDV[t];
  }
}

// ---------------- K7: fully-parallel exact Kruskal pairing (rank-space, tree input) ----------------
__global__ __launch_bounds__(1024) void k_pair(
    const u32* __restrict__ sRK, u32* __restrict__ mrec,
    u32* __restrict__ mtab, u32* __restrict__ tmp,
    u32* __restrict__ remA, u32* __restrict__ remB) {
  __shared__ u16 par[ND + 1];
  __shared__ int nRem, nNxt;
  int tid = threadIdx.x;
  {
    u32* p32 = (u32*)par;
    for (int v = tid; v < (ND + 1) / 2; v += 1024)
      p32[v] = ((2u * v + 1) << 16) | (2u * v);
  }
  if (tid == 0) nRem = NT;
  __syncthreads();
  u32* remCur = remA;
  u32* remNxt = remB;
  for (int round = 0; round < NT + 8; ++round) {
    int R = nRem;
    if (R == 0) break;
    if (tid == 0) nNxt = 0;
    for (int i = tid; i < R; i += 1024) {
      u32 e = (round == 0) ? (u32)i : remCur[i];
      u32 ab = sRK[e];
      int ra = findh((volatile u16*)par, (int)(ab & 0xFFFFu));
      int rb = findh((volatile u16*)par, (int)(ab >> 16));
      u32 y = (u32)max(ra, rb), o = (u32)min(ra, rb);
      tmp[i] = (y << 16) | o;
      atomicMin(&mtab[y], e);
    }
    __syncthreads();
    for (int i = tid; i < R; i += 1024) {
      u32 e = (round == 0) ? (u32)i : remCur[i];
      u32 t = tmp[i];
      u32 y = t >> 16, o = t & 0xFFFFu;
      if (mtab[y] == e) {
        mrec[e] = y;
        par[y] = (u16)o;
      } else {
        int pos = atomicAdd(&nNxt, 1);
        remNxt[pos] = e;
      }
    }
    __syncthreads();
    for (int i = tid; i < R; i += 1024) mtab[tmp[i] >> 16] = 0xFFFFFFFFu;
    for (int v = tid; v < ND; v += 1024) {
      int p = par[v]; int pp = par[p];
      if (p != pp) par[v] = (u16)pp;
    }
    __syncthreads();
    if (tid == 0) nRem = nNxt;
    __syncthreads();
    u32* s = remCur; remCur = remNxt; remNxt = s;
  }
}

// ---------------- K8: max bar reduction ----------------
__global__ void k_final(const u32* __restrict__ mrec, const float* __restrict__ sDV,
                        const float* __restrict__ frv, u32* accU) {
  __shared__ float lm[4];
  int tid = threadIdx.x;
  int idx = blockIdx.x * 256 + tid;
  float bar = 0.f;
  if (idx < NT) bar = frv[mrec[idx]] - sDV[idx];
  for (int off = 32; off >= 1; off >>= 1) bar = fmaxf(bar, __shfl_down(bar, off));
  if ((tid & 63) == 0) lm[tid >> 6] = bar;
  __syncthreads();
  if (tid == 0) {
    float m = fmaxf(fmaxf(lm[0], lm[1]), fmaxf(lm[2], lm[3]));
    atomicMax(&accU[5], fmap(m));
  }
}

// ---------------- K9: assemble output ----------------
__global__ void k_out(const float* __restrict__ accF, const u32* __restrict__ accU, float* out) {
  float wmst = accF[0] - accF[4];                      // primal MST weight via planar duality
  float loss0 = wmst + accF[1] - funmap(accU[2]);
  float sum1 = accF[3] - accF[4];
  float max1 = funmap(accU[5]);
  out[0] = loss0 + sum1 - max1;
}

extern "C" void kernel_launch(void* const* d_in, const int* in_sizes, int n_in,
                              void* d_out, int out_size, void* d_ws, size_t ws_size,
                              hipStream_t stream) {
  const float* beta = (const float*)d_in[0];
  float* out = (float*)d_out;
  char* ws = (char*)d_ws;
  float* accF = (float*)(ws + OFF_ACC);
  u32*   accU = (u32*)(ws + OFF_ACC);
  u32*   gtmp = (u32*)(ws + OFF_ACC + 64);
  u32* r32 = (u32*)(ws + OFF_R32);
  float* fval = (float*)(ws + OFF_FVAL);
  u16* ctv = (u16*)(ws + OFF_CTV);
  u32* cntR = (u32*)(ws + OFF_CNTR);
  u32* frk = (u32*)(ws + OFF_FRK);
  float* frv = (float*)(ws + OFF_FRV);
  float* dvals = (float*)(ws + OFF_DVAL);
  uint2* lA = (uint2*)(ws + OFF_LA);
  uint2* lB = (uint2*)(ws + OFF_LB);
  u32* tmp = (u32*)(ws + OFF_TMP);
  u32* mtab = (u32*)(ws + OFF_MTAB);
  u32* treeKey = (u32*)(ws + OFF_TKEY);
  u32* treeRK = (u32*)(ws + OFF_TRK);   // reused as mrec by k_pair/k_final
  float* treeDV = (float*)(ws + OFF_TDV);
  u32* sRK = (u32*)(ws + OFF_SRK);
  float* sDV = (float*)(ws + OFF_SDV);
  u32* remA = (u32*)(ws + OFF_REMA);
  u32* remB = (u32*)(ws + OFF_REMB);
  u32* mrec = treeRK;

  hipLaunchKernelGGL(k_init, dim3(127), dim3(256), 0, stream, accF, r32, mtab);
  hipLaunchKernelGGL(k_rankv, dim3(64, 16), dim3(256), 0, stream, beta, r32);
  hipLaunchKernelGGL(k_build, dim3(191), dim3(256), 0, stream, beta, r32, fval, ctv, accF, accU);
  hipLaunchKernelGGL(k_cntface, dim3(64), dim3(256), 0, stream, ctv, r32, cntR);
  hipLaunchKernelGGL(k_scanR, dim3(1), dim3(1024), 0, stream, cntR);
  hipLaunchKernelGGL(k_facerank, dim3(127), dim3(256), 0, stream, ctv, r32, cntR, fval, frk, frv);
  hipLaunchKernelGGL(k_edges, dim3(191), dim3(256), 0, stream, beta, r32, dvals, lA, accF);
  hipLaunchKernelGGL(k_mst, dim3(1), dim3(1024), 0, stream, dvals, lA, lB, mtab, tmp, frk,
                     treeKey, treeRK, treeDV, accF);
  hipLaunchKernelGGL(k_sorttree, dim3(1), dim3(1024), 0, stream, treeKey, treeRK, treeDV, sRK, sDV, gtmp);
  hipLaunchKernelGGL(k_pair, dim3(1), dim3(1024), 0, stream, sRK, mrec, mtab, tmp, remA, remB);
  hipLaunchKernelGGL(k_final, dim3(127), dim3(256), 0, stream, mrec, sDV, frv, accU);
  hipLaunchKernelGGL(k_out, dim3(1), dim3(1), 0, stream, accF, accU, out);
}

// Round 6
// 502.085 us; speedup vs baseline: 8.7624x; 1.1755x over previous
//
#include <hip/hip_runtime.h>

#define NV 16384
#define EH 16256
#define EVV 16256
#define ED 16129
#define NE 48641
#define NT 32258
#define ND 32259
#define OUTERF 32258

typedef unsigned int u32;
typedef unsigned short u16;

// ---------------- ws layout ----------------
static __host__ __device__ constexpr size_t al256(size_t x) { return (x + 255) & ~(size_t)255; }
static constexpr size_t OFF_ACC   = 0;                                  // acc[0..6), gtmp at +64
static constexpr size_t OFF_R32   = 256;                                // u32[NV]
static constexpr size_t OFF_FVAL  = OFF_R32   + al256(NV * 4);          // f32[ND]
static constexpr size_t OFF_CTV   = OFF_FVAL  + al256(ND * 4);          // u16[NT]
static constexpr size_t OFF_CNTR  = OFF_CTV   + al256(NT * 2);          // u32[NV]
static constexpr size_t OFF_FRK   = OFF_CNTR  + al256(NV * 4);          // u32[ND]
static constexpr size_t OFF_FRV   = OFF_FRK   + al256(ND * 4);          // f32[ND]
static constexpr size_t OFF_DVAL  = OFF_FRV   + al256(ND * 4);          // f32[NE]
static constexpr size_t OFF_INM   = OFF_DVAL  + al256(NE * 4);          // u32[NE]
static constexpr size_t OFF_WLA   = OFF_INM   + al256(NE * 4);          // u32[NE]
static constexpr size_t OFF_WLB   = OFF_WLA   + al256(NE * 4);          // u32[NE]
static constexpr size_t OFF_SRK   = OFF_WLB   + al256(NE * 4);          // u32[NT]
static constexpr size_t OFF_SDV   = OFF_SRK   + al256(NT * 4);          // f32[NT]
static constexpr size_t OFF_MREC  = OFF_SDV   + al256(NT * 4);          // u32[NT]
static constexpr size_t OFF_REMA  = OFF_MREC  + al256(NT * 4);          // u32[NT]
static constexpr size_t OFF_REMB  = OFF_REMA  + al256(NT * 4);          // u32[NT]

__device__ __forceinline__ u32 fmap(float x) {
  u32 u = __float_as_uint(x);
  return (u & 0x80000000u) ? ~u : (u | 0x80000000u);
}
__device__ __forceinline__ float funmap(u32 m) {
  u32 u = (m & 0x80000000u) ? (m & 0x7FFFFFFFu) : ~m;
  return __uint_as_float(u);
}

__device__ __forceinline__ int findh(volatile u16* par, int x) {
  while (true) {
    int p = par[x];
    if (p == x) return x;
    int gp = par[p];
    if (gp == p) return p;
    par[x] = (u16)gp;
    x = gp;
  }
}

// edge eid -> primal endpoints
__device__ __forceinline__ void decode_pe(u32 e, int& eu, int& ev) {
  if (e < EH) { int i = (int)(e / 127u), j = (int)(e - (u32)i * 127u); eu = (i << 7) + j; ev = eu + 1; }
  else if (e < EH + EVV) { int k = (int)(e - EH); eu = k; ev = k + 128; }
  else { int k = (int)(e - EH - EVV); int i = k / 127, j = k - i * 127; eu = (i << 7) + j; ev = eu + 129; }
}
// edge eid -> dual faces
__device__ __forceinline__ void decode_df(u32 e, int& fa, int& fb) {
  if (e < EH) { int i = (int)(e / 127u), j = (int)(e - (u32)i * 127u);
    fa = (i < 127) ? (ED + i * 127 + j) : OUTERF;
    fb = (i >= 1) ? ((i - 1) * 127 + j) : OUTERF; }
  else if (e < EH + EVV) { int k = (int)(e - EH); int i = k >> 7, j = k & 127;
    fa = (j < 127) ? (i * 127 + j) : OUTERF;
    fb = (j >= 1) ? (ED + i * 127 + (j - 1)) : OUTERF; }
  else { int k = (int)(e - EH - EVV); int i = k / 127, j = k - i * 127;
    fa = i * 127 + j; fb = ED + i * 127 + j; }
}

// ---------------- K0: init ----------------
// acc: F[0]=sum dv(all edges), F[1]=sum beta, U[2]=max beta(fmap),
//      F[3]=sum fval(faces), F[4]=sum dv(primal MST), U[5]=max bar(fmap)
__global__ void k_init(float* accF, u32* r32, u32* inMST) {
  int i = blockIdx.x * 256 + threadIdx.x;
  if (i < 6) accF[i] = 0.f;
  if (i < NV) r32[i] = 0u;
  if (i < NE) inMST[i] = 0u;
}

// ---------------- K1: vertex ranks (ascending beta, id tiebreak) ----------------
__global__ void k_rankv(const float* __restrict__ beta, u32* r32) {
  int v = blockIdx.x * 256 + threadIdx.x;
  int c = blockIdx.y;
  float bv = beta[v];
  int u0 = c << 10;
  int cnt = 0;
#pragma unroll 8
  for (int u = u0; u < u0 + 1024; ++u) {
    float bu = beta[u];
    cnt += (bu < bv || (bu == bv && u < v)) ? 1 : 0;
  }
  if (cnt) atomicAdd(&r32[v], (u32)cnt);
}

// ---------------- K2: face values + crit vertex + reductions ----------------
__global__ void k_build(const float* __restrict__ beta, const u32* __restrict__ r32,
                        float* fval, u16* ctv, float* accF, u32* accU) {
  __shared__ float ls[4], lm[4];
  int bid = blockIdx.x, tid = threadIdx.x;
  if (bid < 64) {
    int v = (bid << 8) + tid;
    float b = beta[v];
    float s = b, m = b;
    for (int off = 32; off >= 1; off >>= 1) {
      s += __shfl_down(s, off);
      m = fmaxf(m, __shfl_down(m, off));
    }
    int wid = tid >> 6;
    if ((tid & 63) == 0) { ls[wid] = s; lm[wid] = m; }
    __syncthreads();
    if (tid == 0) {
      s = ls[0] + ls[1] + ls[2] + ls[3];
      m = fmaxf(fmaxf(lm[0], lm[1]), fmaxf(lm[2], lm[3]));
      atomicAdd(&accF[1], s);
      atomicMax(&accU[2], fmap(m));
    }
  } else {
    int t = ((bid - 64) << 8) + tid;
    float c = 0.f;
    if (t < NT) {
      int i, j, v0, v1, v2;
      if (t < ED) { i = t / 127; j = t - i * 127; v0 = (i << 7) + j; v1 = v0 + 128; v2 = v0 + 129; } // L
      else { int u = t - ED; i = u / 127; j = u - i * 127; v0 = (i << 7) + j; v1 = v0 + 1; v2 = v0 + 129; } // U
      u32 r0 = r32[v0], r1 = r32[v1], r2 = r32[v2];
      int crit = v0; u32 rm = r0;
      if (r1 < rm) { rm = r1; crit = v1; }
      if (r2 < rm) { rm = r2; crit = v2; }
      float fv = -beta[crit];
      fval[t] = fv;
      ctv[t] = (u16)crit;
      c = fv;
      if (t == 0) fval[OUTERF] = __builtin_inff();
    }
    for (int off = 32; off >= 1; off >>= 1) c += __shfl_down(c, off);
    int wid = tid >> 6;
    if ((tid & 63) == 0) ls[wid] = c;
    __syncthreads();
    if (tid == 0) atomicAdd(&accF[3], ls[0] + ls[1] + ls[2] + ls[3]);
  }
}

// ---------------- K3a: per-vertex crit-face counts into rank buckets ----------------
__global__ void k_cntface(const u16* __restrict__ ctv, const u32* __restrict__ r32, u32* cntR) {
  int v = blockIdx.x * 256 + threadIdx.x;
  int i = v >> 7, j = v & 127;
  int cnt = 0;
  if (i < 127 && j < 127) cnt += (ctv[i * 127 + j] == v);
  if (i >= 1 && j < 127)  cnt += (ctv[(i - 1) * 127 + j] == v);
  if (i >= 1 && j >= 1)   cnt += (ctv[(i - 1) * 127 + (j - 1)] == v);
  if (i < 127 && j < 127) cnt += (ctv[ED + i * 127 + j] == v);
  if (i < 127 && j >= 1)  cnt += (ctv[ED + i * 127 + (j - 1)] == v);
  if (i >= 1 && j >= 1)   cnt += (ctv[ED + (i - 1) * 127 + (j - 1)] == v);
  cntR[r32[v]] = (u32)cnt;
}

// ---------------- K3b: exclusive scan over NV rank buckets (+1: outer face = rank 0) ----------------
__global__ __launch_bounds__(1024) void k_scanR(u32* cntR) {
  __shared__ u32 wsum[16];
  int tid = threadIdx.x;
  u32 loc[16]; u32 s = 0;
#pragma unroll
  for (int k = 0; k < 16; ++k) { u32 c = cntR[(tid << 4) + k]; loc[k] = s; s += c; }
  int lane = tid & 63, wid = tid >> 6;
  u32 incl = s;
  for (int off = 1; off < 64; off <<= 1) {
    u32 o = __shfl_up(incl, off);
    if (lane >= off) incl += o;
  }
  if (lane == 63) wsum[wid] = incl;
  __syncthreads();
  u32 wbase = 0;
  for (int w = 0; w < wid; ++w) wbase += wsum[w];
  u32 base = wbase + incl - s + 1;
#pragma unroll
  for (int k = 0; k < 16; ++k) cntR[(tid << 4) + k] = base + loc[k];
}

// ---------------- K3c: face ranks + rank->value table ----------------
__global__ void k_facerank(const u16* __restrict__ ctv, const u32* __restrict__ r32,
                           const u32* __restrict__ startsR, const float* __restrict__ fval,
                           u32* frk, float* frv) {
  int g = blockIdx.x * 256 + threadIdx.x;
  if (g == 0) { frk[OUTERF] = 0u; frv[0] = __builtin_inff(); }
  if (g >= NT) return;
  int v = ctv[g];
  int i = v >> 7, j = v & 127;
  int local = 0, f;
  if (i < 127 && j < 127) { f = i * 127 + j;             local += (f < g && ctv[f] == v); }
  if (i >= 1 && j < 127)  { f = (i - 1) * 127 + j;       local += (f < g && ctv[f] == v); }
  if (i >= 1 && j >= 1)   { f = (i - 1) * 127 + (j - 1); local += (f < g && ctv[f] == v); }
  if (i < 127 && j < 127) { f = ED + i * 127 + j;        local += (f < g && ctv[f] == v); }
  if (i < 127 && j >= 1)  { f = ED + i * 127 + (j - 1);  local += (f < g && ctv[f] == v); }
  if (i >= 1 && j >= 1)   { f = ED + (i - 1) * 127 + (j - 1); local += (f < g && ctv[f] == v); }
  u32 rk = startsR[r32[v]] + (u32)local;
  frk[g] = rk;
  frv[rk] = fval[g];
}

// ---------------- K4: edge values + total sum ----------------
__global__ void k_edges(const float* __restrict__ beta, const u32* __restrict__ r32,
                        float* dvals, float* accF) {
  int e = blockIdx.x * 256 + threadIdx.x;
  float dv = 0.f;
  if (e < NE) {
    int eu, ev; decode_pe((u32)e, eu, ev);
    u32 ru = r32[eu], rv = r32[ev];
    int cv = (ru <= rv) ? eu : ev;
    dv = -beta[cv];
    dvals[e] = dv;
  }
  float ds = dv;
  for (int off = 32; off >= 1; off >>= 1) ds += __shfl_down(ds, off);
  if ((threadIdx.x & 63) == 0) atomicAdd(&accF[0], ds);
}

// ---------------- K5: PRIMAL MST, all state in LDS (claim-both-roots) ----------------
// Ascending-f key = ((16383-rr)<<17)|e, rr = rank of min-beta endpoint (unique keys).
// P2 recomputes finds: a winner's won root can only be hooked by the winner itself,
// so its root is round-stable; losers requeue / cycle edges drop (both conservative).
__global__ __launch_bounds__(1024) void k_mst(
    const u32* __restrict__ r32g, const float* __restrict__ dvals,
    u32* __restrict__ wlA, u32* __restrict__ wlB,
    u32* __restrict__ inMST, float* accF) {
  __shared__ u16 parL[NV];
  __shared__ u16 r16[NV];
  __shared__ u32 mtabL[NV];
  __shared__ int nCur, nNxt;
  __shared__ float wred[16];
  int tid = threadIdx.x;
  for (int v = tid; v < NV; v += 1024) {
    parL[v] = (u16)v;
    r16[v] = (u16)r32g[v];
    mtabL[v] = 0xFFFFFFFFu;
  }
  if (tid == 0) { nCur = NE; nNxt = 0; }
  float wloc = 0.f;
  __syncthreads();
  u32* cur = wlA;
  u32* nxt = wlB;
  for (int round = 0; round < 24; ++round) {
    int n = nCur;
    if (n == 0) break;
    // P1: claim both roots
    for (int i = tid; i < n; i += 1024) {
      u32 e = (round == 0) ? (u32)i : cur[i];
      int eu, ev; decode_pe(e, eu, ev);
      int ra = findh((volatile u16*)parL, eu);
      int rb = findh((volatile u16*)parL, ev);
      if (ra == rb) continue;
      u32 rr = min((u32)r16[eu], (u32)r16[ev]);
      u32 kk = ((16383u - rr) << 17) | e;
      atomicMin(&mtabL[ra], kk);
      atomicMin(&mtabL[rb], kk);
    }
    __syncthreads();
    // P2: winners commit + hook; losers requeue; cycles drop
    for (int i = tid; i < n; i += 1024) {
      u32 e = (round == 0) ? (u32)i : cur[i];
      int eu, ev; decode_pe(e, eu, ev);
      int ra = findh((volatile u16*)parL, eu);
      int rb = findh((volatile u16*)parL, ev);
      if (ra == rb) continue;
      u32 rr = min((u32)r16[eu], (u32)r16[ev]);
      u32 kk = ((16383u - rr) << 17) | e;
      bool wa = (mtabL[ra] == kk), wb = (mtabL[rb] == kk);
      if (wa | wb) {
        inMST[e] = 1u;
        wloc += dvals[e];
        if (wa && wb) { int y = max(ra, rb), o = min(ra, rb); parL[y] = (u16)o; }
        else if (wa) parL[ra] = (u16)rb;
        else parL[rb] = (u16)ra;
      } else {
        nxt[atomicAdd(&nNxt, 1)] = e;
      }
    }
    __syncthreads();
    // P3: full claim reset + one compression sweep
    for (int v = tid; v < NV; v += 1024) {
      mtabL[v] = 0xFFFFFFFFu;
      int p = parL[v]; int pp = parL[p];
      if (p != pp) parL[v] = (u16)pp;
    }
    __syncthreads();
    if (tid == 0) { nCur = nNxt; nNxt = 0; }
    __syncthreads();
    u32* s = cur; cur = nxt; nxt = s;
  }
  for (int off = 32; off >= 1; off >>= 1) wloc += __shfl_down(wloc, off);
  if ((tid & 63) == 0) wred[tid >> 6] = wloc;
  __syncthreads();
  if (tid == 0) {
    float s = 0.f;
    for (int w = 0; w < 16; ++w) s += wred[w];
    atomicAdd(&accF[4], s);
  }
}

// ---------------- K6: counting-sort COMPLEMENT (dual maxST) by crit rank ----------------
__global__ __launch_bounds__(1024) void k_sorttree(
    const u32* __restrict__ inMST, const u32* __restrict__ r32,
    const float* __restrict__ dvals, const u32* __restrict__ frk,
    u32* sRK, float* sDV, u32* gtmp) {
  __shared__ u32 cnt[NV];
  int tid = threadIdx.x;
  for (int b = tid; b < NV; b += 1024) cnt[b] = 0u;
  __syncthreads();
  for (int e = tid; e < NE; e += 1024) {
    if (inMST[e]) continue;
    int eu, ev; decode_pe((u32)e, eu, ev);
    u32 rr = min(r32[eu], r32[ev]);
    atomicAdd(&cnt[rr], 1u);
  }
  __syncthreads();
  u32 loc[16]; u32 s = 0;
#pragma unroll
  for (int k = 0; k < 16; ++k) { loc[k] = s; s += cnt[(tid << 4) + k]; }
  int lane = tid & 63, wid = tid >> 6;
  u32 incl = s;
  for (int off = 1; off < 64; off <<= 1) {
    u32 o = __shfl_up(incl, off);
    if (lane >= off) incl += o;
  }
  if (lane == 63) gtmp[wid] = incl;
  __syncthreads();
  u32 wbase = 0;
  for (int w = 0; w < 16; ++w) { u32 tt = gtmp[w]; wbase += (w < wid) ? tt : 0u; }
  u32 base = wbase + incl - s;
#pragma unroll
  for (int k = 0; k < 16; ++k) cnt[(tid << 4) + k] = base + loc[k];
  __syncthreads();
  for (int e = tid; e < NE; e += 1024) {
    if (inMST[e]) continue;
    int eu, ev; decode_pe((u32)e, eu, ev);
    u32 rr = min(r32[eu], r32[ev]);
    int fa, fb; decode_df((u32)e, fa, fb);
    u32 pos = atomicAdd(&cnt[rr], 1u);
    sRK[pos] = frk[fa] | (frk[fb] << 16);
    sDV[pos] = dvals[e];
  }
}

// ---------------- K7: exact parallel Kruskal pairing, all state in LDS ----------------
// par over rank-space faces; hashed claim table mt[16384] (h=y&16383): strictly
// stronger commit criterion (collision losers requeue) => still exact; slot-holder's
// younger root is round-stable => P2 recompute is safe.
__global__ __launch_bounds__(1024) void k_pair(
    const u32* __restrict__ sRK, u32* __restrict__ mrec,
    u32* __restrict__ remA, u32* __restrict__ remB) {
  __shared__ u16 par[ND + 1];
  __shared__ u32 mt[16384];
  __shared__ int nRem, nNxt;
  int tid = threadIdx.x;
  {
    u32* p32 = (u32*)par;
    for (int v = tid; v < (ND + 1) / 2; v += 1024)
      p32[v] = ((2u * v + 1) << 16) | (2u * v);
  }
  for (int v = tid; v < 16384; v += 1024) mt[v] = 0xFFFFFFFFu;
  if (tid == 0) { nRem = NT; nNxt = 0; }
  __syncthreads();
  u32* cur = remA;
  u32* nxt = remB;
  for (int round = 0; round < NT + 8; ++round) {
    int R = nRem;
    if (R == 0) break;
    // P1: find + hashed claim
    for (int i = tid; i < R; i += 1024) {
      u32 e = (round == 0) ? (u32)i : cur[i];
      u32 ab = sRK[e];
      int ra = findh((volatile u16*)par, (int)(ab & 0xFFFFu));
      int rb = findh((volatile u16*)par, (int)(ab >> 16));
      u32 y = (u32)max(ra, rb);
      atomicMin(&mt[y & 16383u], e);
    }
    __syncthreads();
    // P2: winners commit (recomputed roots), losers requeue
    for (int i = tid; i < R; i += 1024) {
      u32 e = (round == 0) ? (u32)i : cur[i];
      u32 ab = sRK[e];
      int ra = findh((volatile u16*)par, (int)(ab & 0xFFFFu));
      int rb = findh((volatile u16*)par, (int)(ab >> 16));
      u32 y = (u32)max(ra, rb), o = (u32)min(ra, rb);
      if (mt[y & 16383u] == e) {
        mrec[e] = y;
        par[y] = (u16)o;
      } else {
        nxt[atomicAdd(&nNxt, 1)] = e;
      }
    }
    __syncthreads();
    // P3: reset claims + compress
    for (int v = tid; v < 16384; v += 1024) mt[v] = 0xFFFFFFFFu;
    for (int v = tid; v < ND; v += 1024) {
      int p = par[v]; int pp = par[p];
      if (p != pp) par[v] = (u16)pp;
    }
    __syncthreads();
    if (tid == 0) { nRem = nNxt; nNxt = 0; }
    __syncthreads();
    u32* s = cur; cur = nxt; nxt = s;
  }
}

// ---------------- K8: max bar reduction ----------------
__global__ void k_final(const u32* __restrict__ mrec, const float* __restrict__ sDV,
                        const float* __restrict__ frv, u32* accU) {
  __shared__ float lm[4];
  int tid = threadIdx.x;
  int idx = blockIdx.x * 256 + tid;
  float bar = 0.f;
  if (idx < NT) bar = frv[mrec[idx]] - sDV[idx];
  for (int off = 32; off >= 1; off >>= 1) bar = fmaxf(bar, __shfl_down(bar, off));
  if ((tid & 63) == 0) lm[tid >> 6] = bar;
  __syncthreads();
  if (tid == 0) {
    float m = fmaxf(fmaxf(lm[0], lm[1]), fmaxf(lm[2], lm[3]));
    atomicMax(&accU[5], fmap(m));
  }
}

// ---------------- K9: assemble output ----------------
__global__ void k_out(const float* __restrict__ accF, const u32* __restrict__ accU, float* out) {
  float pms = accF[4];                                  // primal MST f-sum
  float loss0 = pms + accF[1] - funmap(accU[2]);
  float sum1 = accF[3] - (accF[0] - pms);               // faces - dual-tree sum
  float max1 = funmap(accU[5]);
  out[0] = loss0 + sum1 - max1;
}

extern "C" void kernel_launch(void* const* d_in, const int* in_sizes, int n_in,
                              void* d_out, int out_size, void* d_ws, size_t ws_size,
                              hipStream_t stream) {
  const float* beta = (const float*)d_in[0];
  float* out = (float*)d_out;
  char* ws = (char*)d_ws;
  float* accF = (float*)(ws + OFF_ACC);
  u32*   accU = (u32*)(ws + OFF_ACC);
  u32*   gtmp = (u32*)(ws + OFF_ACC + 64);
  u32* r32 = (u32*)(ws + OFF_R32);
  float* fval = (float*)(ws + OFF_FVAL);
  u16* ctv = (u16*)(ws + OFF_CTV);
  u32* cntR = (u32*)(ws + OFF_CNTR);
  u32* frk = (u32*)(ws + OFF_FRK);
  float* frv = (float*)(ws + OFF_FRV);
  float* dvals = (float*)(ws + OFF_DVAL);
  u32* inMST = (u32*)(ws + OFF_INM);
  u32* wlA = (u32*)(ws + OFF_WLA);
  u32* wlB = (u32*)(ws + OFF_WLB);
  u32* sRK = (u32*)(ws + OFF_SRK);
  float* sDV = (float*)(ws + OFF_SDV);
  u32* mrec = (u32*)(ws + OFF_MREC);
  u32* remA = (u32*)(ws + OFF_REMA);
  u32* remB = (u32*)(ws + OFF_REMB);

  hipLaunchKernelGGL(k_init, dim3(191), dim3(256), 0, stream, accF, r32, inMST);
  hipLaunchKernelGGL(k_rankv, dim3(64, 16), dim3(256), 0, stream, beta, r32);
  hipLaunchKernelGGL(k_build, dim3(191), dim3(256), 0, stream, beta, r32, fval, ctv, accF, accU);
  hipLaunchKernelGGL(k_cntface, dim3(64), dim3(256), 0, stream, ctv, r32, cntR);
  hipLaunchKernelGGL(k_scanR, dim3(1), dim3(1024), 0, stream, cntR);
  hipLaunchKernelGGL(k_facerank, dim3(127), dim3(256), 0, stream, ctv, r32, cntR, fval, frk, frv);
  hipLaunchKernelGGL(k_edges, dim3(191), dim3(256), 0, stream, beta, r32, dvals, accF);
  hipLaunchKernelGGL(k_mst, dim3(1), dim3(1024), 0, stream, r32, dvals, wlA, wlB, inMST, accF);
  hipLaunchKernelGGL(k_sorttree, dim3(1), dim3(1024), 0, stream, inMST, r32, dvals, frk, sRK, sDV, gtmp);
  hipLaunchKernelGGL(k_pair, dim3(1), dim3(1024), 0, stream, sRK, mrec, remA, remB);
  hipLaunchKernelGGL(k_final, dim3(127), dim3(256), 0, stream, mrec, sDV, frv, accU);
  hipLaunchKernelGGL(k_out, dim3(1), dim3(1), 0, stream, accF, accU, out);
}